// Round 5
// baseline (452.591 us; speedup 1.0000x reference)
//
#include <hip/hip_runtime.h>
#include <stdint.h>
#include <stddef.h>

#define NB  64
#define ND  256
#define NLC 1024
#define NLQ 128
#define INVKEEP (1.0f/0.9f)

// ---- workspace layout (float offsets) ----
#define OFF_SQ    0u            // NB*NLQ
#define OFF_RMAX  8192u         // NB*NLC  (row max of S)
#define OFF_RSUM  73728u        // NB*NLC  (RECIPROCAL row sum)
#define OFF_CMAX  139264u       // NB*NLQ  (col max)
#define OFF_CSUM  147456u       // NB*NLQ  (RECIPROCAL col sum)
#define OFF_S     155648u       // NB*NLC*NLQ (raw S)
#define OFF_M     8544256u      // 2*NB*ND*NLQ (split-K partial M)

typedef float f32x4  __attribute__((ext_vector_type(4)));
typedef short bf16x8 __attribute__((ext_vector_type(8)));

// bf16 helpers: RNE pack
__device__ __forceinline__ uint32_t f2bf(float x) {
  const uint32_t u = __float_as_uint(x);
  return (u + 0x7fffu + ((u >> 16) & 1u)) >> 16;
}

// ================= threefry2x32, key=(0,42); bits = o0^o1 (verified r2) =====
__device__ __forceinline__ void tf_round(uint32_t& a, uint32_t& b, const int r) {
  a += b;
  b = (b << r) | (b >> (32 - r));
  b ^= a;
}
__device__ __forceinline__ uint32_t threefry_xor(uint32_t x0, uint32_t x1) {
  const uint32_t ks0 = 0u, ks1 = 42u, ks2 = 0x1BD11BDAu ^ 0u ^ 42u;
  x0 += ks0; x1 += ks1;
  tf_round(x0,x1,13); tf_round(x0,x1,15); tf_round(x0,x1,26); tf_round(x0,x1,6);
  x0 += ks1; x1 += ks2 + 1u;
  tf_round(x0,x1,17); tf_round(x0,x1,29); tf_round(x0,x1,16); tf_round(x0,x1,24);
  x0 += ks2; x1 += ks0 + 2u;
  tf_round(x0,x1,13); tf_round(x0,x1,15); tf_round(x0,x1,26); tf_round(x0,x1,6);
  x0 += ks0; x1 += ks1 + 3u;
  tf_round(x0,x1,17); tf_round(x0,x1,29); tf_round(x0,x1,16); tf_round(x0,x1,24);
  x0 += ks1; x1 += ks2 + 4u;
  tf_round(x0,x1,13); tf_round(x0,x1,15); tf_round(x0,x1,26); tf_round(x0,x1,6);
  x0 += ks2; x1 += ks0 + 5u;
  return x0 ^ x1;
}

// ================= sq[b,j] = sum_d wq[d] * Q[b,d,j] ==========================
__global__ __launch_bounds__(128) void k_sq(const float* __restrict__ Q,
                                            const float* __restrict__ W,
                                            float* __restrict__ ws) {
  const int b = blockIdx.x;
  const int j = threadIdx.x;
  const float* wq = W + (size_t)b*768;
  const float* Qb = Q + (size_t)b*ND*NLQ;
  float acc = 0.0f;
  for (int d = 0; d < ND; ++d) acc = fmaf(wq[d], Qb[(size_t)d*NLQ + j], acc);
  ws[OFF_SQ + (size_t)b*NLQ + j] = acc;
}

// ========== S[b,i,j] = sum_d C[d,i]*(wm[d]*Q[d,j]+wc[d]) + sq[j] ============
__global__ __launch_bounds__(256) void k_s(const float* __restrict__ C,
                                           const float* __restrict__ Q,
                                           const float* __restrict__ W,
                                           float* __restrict__ ws) {
  __shared__ float Cs[32][64];
  __shared__ float Qs[32][128];
  __shared__ float wmS[256], wcS[256], sqS[128];
  const int b  = blockIdx.y;
  const int i0 = blockIdx.x * 64;
  const int t  = threadIdx.x;
  const int jg = t & 15;        // j = jg*8 .. +7
  const int ig = t >> 4;        // i = i0 + ig*4 .. +3
  wcS[t] = W[(size_t)b*768 + 256 + t];
  wmS[t] = W[(size_t)b*768 + 512 + t];
  if (t < 128) sqS[t] = ws[OFF_SQ + (size_t)b*NLQ + t];

  float acc[4][8];
  #pragma unroll
  for (int r = 0; r < 4; ++r)
    #pragma unroll
    for (int x = 0; x < 8; ++x) acc[r][x] = 0.0f;

  const float* Cb = C + (size_t)b*ND*NLC;
  const float* Qb = Q + (size_t)b*ND*NLQ;

  for (int d0 = 0; d0 < ND; d0 += 32) {
    __syncthreads();
    #pragma unroll
    for (int r = 0; r < 2; ++r) {
      const int f = r*256 + t;
      const int dk = f >> 4, i4 = f & 15;
      *(float4*)&Cs[dk][i4*4] = *(const float4*)&Cb[(size_t)(d0+dk)*NLC + i0 + i4*4];
    }
    #pragma unroll
    for (int r = 0; r < 4; ++r) {
      const int f = r*256 + t;
      const int dk = f >> 5, j4 = f & 31;
      const float4 qv = *(const float4*)&Qb[(size_t)(d0+dk)*NLQ + j4*4];
      const float wmv = wmS[d0+dk], wcv = wcS[d0+dk];
      float4 o;
      o.x = fmaf(wmv, qv.x, wcv);
      o.y = fmaf(wmv, qv.y, wcv);
      o.z = fmaf(wmv, qv.z, wcv);
      o.w = fmaf(wmv, qv.w, wcv);
      *(float4*)&Qs[dk][j4*4] = o;
    }
    __syncthreads();
    #pragma unroll
    for (int dk = 0; dk < 32; ++dk) {
      const float4 cq = *(const float4*)&Cs[dk][ig*4];
      const float4 q0 = *(const float4*)&Qs[dk][jg*8];
      const float4 q1 = *(const float4*)&Qs[dk][jg*8+4];
      const float cr[4] = {cq.x, cq.y, cq.z, cq.w};
      const float qv[8] = {q0.x,q0.y,q0.z,q0.w,q1.x,q1.y,q1.z,q1.w};
      #pragma unroll
      for (int r = 0; r < 4; ++r)
        #pragma unroll
        for (int x = 0; x < 8; ++x)
          acc[r][x] = fmaf(cr[r], qv[x], acc[r][x]);
    }
  }

  float sqv[8];
  #pragma unroll
  for (int x = 0; x < 8; ++x) sqv[x] = sqS[jg*8 + x];
  float* Sb = ws + OFF_S + ((size_t)b*NLC + (size_t)i0)*NLQ;
  #pragma unroll
  for (int r = 0; r < 4; ++r) {
    float sv[8];
    #pragma unroll
    for (int x = 0; x < 8; ++x) sv[x] = acc[r][x] + sqv[x];
    float m = sv[0];
    #pragma unroll
    for (int x = 1; x < 8; ++x) m = fmaxf(m, sv[x]);
    m = fmaxf(m, __shfl_xor(m, 1));
    m = fmaxf(m, __shfl_xor(m, 2));
    m = fmaxf(m, __shfl_xor(m, 4));
    m = fmaxf(m, __shfl_xor(m, 8));
    float s = 0.0f;
    #pragma unroll
    for (int x = 0; x < 8; ++x) s += __expf(sv[x] - m);
    s += __shfl_xor(s, 1);
    s += __shfl_xor(s, 2);
    s += __shfl_xor(s, 4);
    s += __shfl_xor(s, 8);
    const int row = ig*4 + r;
    *(float4*)&Sb[(size_t)row*NLQ + jg*8]     = make_float4(sv[0],sv[1],sv[2],sv[3]);
    *(float4*)&Sb[(size_t)row*NLQ + jg*8 + 4] = make_float4(sv[4],sv[5],sv[6],sv[7]);
    if (jg == 0) {
      ws[OFF_RMAX + (size_t)b*NLC + i0 + row] = m;
      ws[OFF_RSUM + (size_t)b*NLC + i0 + row] = 1.0f / s;
    }
  }
}

// ============ column softmax stats over i (axis=1): cmax, 1/csum ============
__global__ __launch_bounds__(256) void k_colstats(float* __restrict__ ws) {
  __shared__ float red[8][32];
  const int b  = blockIdx.y;
  const int jq = blockIdx.x;
  const int tx = threadIdx.x & 31;
  const int ty = threadIdx.x >> 5;
  const int j  = jq*32 + tx;
  const float* Sb = ws + OFF_S + (size_t)b*NLC*NLQ;
  float m = -3.0e38f;
  for (int ii = 0; ii < 128; ++ii)
    m = fmaxf(m, Sb[(size_t)(ty*128 + ii)*NLQ + j]);
  red[ty][tx] = m;
  __syncthreads();
  if (ty == 0) {
    #pragma unroll
    for (int y = 1; y < 8; ++y) m = fmaxf(m, red[y][tx]);
    red[0][tx] = m;
  }
  __syncthreads();
  const float cm = red[0][tx];
  __syncthreads();
  float s = 0.0f;
  for (int ii = 0; ii < 128; ++ii)
    s += __expf(Sb[(size_t)(ty*128 + ii)*NLQ + j] - cm);
  red[ty][tx] = s;
  __syncthreads();
  if (ty == 0) {
    #pragma unroll
    for (int y = 1; y < 8; ++y) s += red[y][tx];
    ws[OFF_CMAX + (size_t)b*NLQ + j] = cm;
    ws[OFF_CSUM + (size_t)b*NLQ + j] = 1.0f / s;
  }
}

// ======= M[b,d,j] = sum_k C[b,d,k] * S__[b,k,j]  (split-K=2, d-split=4) =====
// 1D grid 512, XCD-grouped: the 4 dq-blocks of one (ksp,b) share an XCD L2
// so the S half-slab (256 KB) is fetched ~once per group.
__global__ __launch_bounds__(256) void k_m(const float* __restrict__ C,
                                           float* __restrict__ ws) {
  __shared__ float Ps[32][128];
  __shared__ float Csh[32][68];
  __shared__ float cmS[128], icS[128];
  const int n   = blockIdx.x;
  const int rr  = n & 7, qq = n >> 3;
  const int dq  = qq & 3;               // member: d quarter
  const int g   = (qq >> 2) * 8 + rr;   // group 0..127 = (ksp,b)
  const int b   = g & 63;
  const int ksp = g >> 6;
  const int t   = threadIdx.x;
  const int jg  = t & 15;
  const int dg  = t >> 4;
  if (t < 128) {
    cmS[t] = ws[OFF_CMAX + (size_t)b*NLQ + t];
    icS[t] = ws[OFF_CSUM + (size_t)b*NLQ + t];
  }
  float acc[4][8];
  #pragma unroll
  for (int r = 0; r < 4; ++r)
    #pragma unroll
    for (int x = 0; x < 8; ++x) acc[r][x] = 0.0f;

  const float* Cb = C + (size_t)b*ND*NLC + (size_t)dq*64*NLC;
  const float* Sb = ws + OFF_S + (size_t)b*NLC*NLQ;
  const int kbase = ksp * 512;

  for (int kt = 0; kt < 16; ++kt) {
    const int k0 = kbase + kt*32;
    __syncthreads();
    #pragma unroll
    for (int r = 0; r < 4; ++r) {
      const int f = r*256 + t;
      const int kk = f >> 5, j4 = f & 31;
      const float4 sv = *(const float4*)&Sb[(size_t)(k0+kk)*NLQ + j4*4];
      const int j = j4*4;
      float4 p;
      p.x = __expf(sv.x - cmS[j+0]) * icS[j+0];
      p.y = __expf(sv.y - cmS[j+1]) * icS[j+1];
      p.z = __expf(sv.z - cmS[j+2]) * icS[j+2];
      p.w = __expf(sv.w - cmS[j+3]) * icS[j+3];
      *(float4*)&Ps[kk][j4*4] = p;
    }
    #pragma unroll
    for (int r = 0; r < 2; ++r) {
      const int f = r*256 + t;
      const int kq = f & 7, dl = f >> 3;
      const float4 cv = *(const float4*)&Cb[(size_t)dl*NLC + k0 + kq*4];
      Csh[kq*4+0][dl] = cv.x;
      Csh[kq*4+1][dl] = cv.y;
      Csh[kq*4+2][dl] = cv.z;
      Csh[kq*4+3][dl] = cv.w;
    }
    __syncthreads();
    #pragma unroll
    for (int kk = 0; kk < 32; ++kk) {
      const float4 c4 = *(const float4*)&Csh[kk][dg*4];
      const float4 p0 = *(const float4*)&Ps[kk][jg*8];
      const float4 p1 = *(const float4*)&Ps[kk][jg*8+4];
      const float cr[4] = {c4.x,c4.y,c4.z,c4.w};
      const float pv[8] = {p0.x,p0.y,p0.z,p0.w,p1.x,p1.y,p1.z,p1.w};
      #pragma unroll
      for (int r = 0; r < 4; ++r)
        #pragma unroll
        for (int x = 0; x < 8; ++x)
          acc[r][x] = fmaf(cr[r], pv[x], acc[r][x]);
    }
  }
  float* Mp = ws + OFF_M + ((size_t)ksp*NB + b)*ND*NLQ + (size_t)dq*64*NLQ;
  #pragma unroll
  for (int r = 0; r < 4; ++r) {
    const int d = dg*4 + r;
    *(float4*)&Mp[(size_t)d*NLQ + jg*8]     = make_float4(acc[r][0],acc[r][1],acc[r][2],acc[r][3]);
    *(float4*)&Mp[(size_t)d*NLQ + jg*8 + 4] = make_float4(acc[r][4],acc[r][5],acc[r][6],acc[r][7]);
  }
}

// ==== final (MFMA): A = Q*S_^T, Bm = M*S_^T, out = [C, A, C*A, C*Bm] ========
// Natural-layout bf16 LDS tiles; XOR swizzle col ^= (row&7)<<3 (16B granule).
// Dropout mask (threefry) computed INLINE in the epilogue — hides ~5.4e9 int
// VALU ops under the memory-bound write phase (k_mask kernel eliminated).
// 1D grid 2048, XCD-grouped: 4 d-blocks of one (i0,b) share an XCD L2.
__global__ __launch_bounds__(256, 2) void k_final(const float* __restrict__ C,
                                                  const float* __restrict__ Q,
                                                  float* __restrict__ ws,
                                                  float* __restrict__ out) {
  __shared__ ushort St[128][128];       // [i][j] bf16, swizzled
  __shared__ ushort Qt[64][128];        // [d][j] bf16, swizzled
  __shared__ ushort Mt[64][128];        // [d][j] bf16 (M0+M1), swizzled
  const int n  = blockIdx.x;
  const int rr = n & 7, qq = n >> 3;
  const int m  = qq & 3;                // member: d0 block
  const int g  = (qq >> 2) * 8 + rr;    // group 0..511 = (i0,b)
  const int b  = g & 63;
  const int i0 = (g >> 6) * 128;
  const int d0 = m * 64;
  const int t  = threadIdx.x;

  // --- stage S_ (row-softmax applied) as bf16 rows ---
  const float* Sb  = ws + OFF_S + ((size_t)b*NLC + (size_t)i0)*NLQ;
  const float* rmp = ws + OFF_RMAX + (size_t)b*NLC + i0;
  const float* irp = ws + OFF_RSUM + (size_t)b*NLC + i0;
  #pragma unroll
  for (int p = 0; p < 16; ++p) {
    const int f  = p*256 + t;
    const int j4 = f & 31;              // 4 consecutive j
    const int il = f >> 5;              // row 0..127
    const float4 sv = *(const float4*)&Sb[(size_t)il*NLQ + j4*4];
    const float rm = rmp[il], ir = irp[il];
    uint2 pk;
    pk.x = f2bf(__expf(sv.x - rm) * ir) | (f2bf(__expf(sv.y - rm) * ir) << 16);
    pk.y = f2bf(__expf(sv.z - rm) * ir) | (f2bf(__expf(sv.w - rm) * ir) << 16);
    *(uint2*)&St[il][(j4*4) ^ ((il & 7) << 3)] = pk;
  }
  // --- stage Q and M (=M0+M1) as bf16 rows ---
  const float* Qb  = Q + (size_t)b*ND*NLQ + (size_t)d0*NLQ;
  const float* M0p = ws + OFF_M + (size_t)b*ND*NLQ + (size_t)d0*NLQ;
  const float* M1p = M0p + (size_t)NB*ND*NLQ;
  #pragma unroll
  for (int p = 0; p < 8; ++p) {
    const int f  = p*256 + t;
    const int j4 = f & 31;
    const int dl = f >> 5;              // row 0..63
    const int col = (j4*4) ^ ((dl & 7) << 3);
    const float4 qv = *(const float4*)&Qb[(size_t)dl*NLQ + j4*4];
    uint2 pq;
    pq.x = f2bf(qv.x) | (f2bf(qv.y) << 16);
    pq.y = f2bf(qv.z) | (f2bf(qv.w) << 16);
    *(uint2*)&Qt[dl][col] = pq;
    const float4 m0 = *(const float4*)&M0p[(size_t)dl*NLQ + j4*4];
    const float4 m1 = *(const float4*)&M1p[(size_t)dl*NLQ + j4*4];
    uint2 pm;
    pm.x = f2bf(m0.x + m1.x) | (f2bf(m0.y + m1.y) << 16);
    pm.y = f2bf(m0.z + m1.z) | (f2bf(m0.w + m1.w) << 16);
    *(uint2*)&Mt[dl][col] = pm;
  }
  __syncthreads();

  // --- MFMA main loop: wave w owns d-rows [w*16, w*16+16) ---
  const int w  = t >> 6;
  const int l  = t & 63;
  const int lm = l & 15;                // 16-dim index (m for A, n for B/D)
  const int lk = (l >> 4) * 8;          // k sub-offset
  const int sw = (lm & 7) << 3;         // row-swizzle (row&7 == lm&7 everywhere)

  f32x4 accA[8], accB[8];
  #pragma unroll
  for (int f = 0; f < 8; ++f) { accA[f] = (f32x4)0.0f; accB[f] = (f32x4)0.0f; }

  #pragma unroll
  for (int ks = 0; ks < 4; ++ks) {
    const int koff = (ks*32 + lk) ^ sw;
    const bf16x8 qf = *(const bf16x8*)&Qt[w*16 + lm][koff];
    const bf16x8 mf = *(const bf16x8*)&Mt[w*16 + lm][koff];
    #pragma unroll
    for (int f = 0; f < 8; ++f) {
      const bf16x8 sf = *(const bf16x8*)&St[f*16 + lm][koff];
      accA[f] = __builtin_amdgcn_mfma_f32_16x16x32_bf16(qf, sf, accA[f], 0, 0, 0);
      accB[f] = __builtin_amdgcn_mfma_f32_16x16x32_bf16(mf, sf, accB[f], 0, 0, 0);
    }
  }

  // --- epilogue: D frag layout col(=i)=lane&15, row(=d)=(lane>>4)*4+reg ---
  // dropout bit computed inline: bit(nb) = (threefry_xor(0,nb) -> u) < 0.9
  const float* Cb = C + (size_t)b*ND*NLC;
  const int dbase = d0 + w*16 + (l >> 4)*4;
  #pragma unroll
  for (int f = 0; f < 8; ++f) {
    const int i = i0 + f*16 + lm;
    #pragma unroll
    for (int r = 0; r < 4; ++r) {
      const int d = dbase + r;
      const float c = Cb[(size_t)d*NLC + i];
      const float a  = accA[f][r];
      const float bm = accB[f][r];
      const float vals[4] = {c, a, c*a, c*bm};
      #pragma unroll
      for (int s = 0; s < 4; ++s) {
        const uint32_t nb = ((((uint32_t)b << 10) + (uint32_t)(s*ND + d)) << 10)
                            + (uint32_t)i;
        const uint32_t bits = threefry_xor(0u, nb);
        const float u = __uint_as_float((bits >> 9) | 0x3f800000u) - 1.0f;
        out[nb] = (u < 0.9f) ? vals[s] * INVKEEP : 0.0f;
      }
    }
  }
}

extern "C" void kernel_launch(void* const* d_in, const int* in_sizes, int n_in,
                              void* d_out, int out_size, void* d_ws, size_t ws_size,
                              hipStream_t stream) {
  (void)in_sizes; (void)n_in; (void)out_size; (void)ws_size;
  const float* C = (const float*)d_in[0];
  const float* Q = (const float*)d_in[1];
  const float* W = (const float*)d_in[2];
  float* out = (float*)d_out;
  float* ws  = (float*)d_ws;

  hipLaunchKernelGGL(k_sq,       dim3(NB),     dim3(128), 0, stream, Q, W, ws);
  hipLaunchKernelGGL(k_s,        dim3(16, NB), dim3(256), 0, stream, C, Q, W, ws);
  hipLaunchKernelGGL(k_colstats, dim3(4, NB),  dim3(256), 0, stream, ws);
  hipLaunchKernelGGL(k_m,        dim3(512),    dim3(256), 0, stream, C, ws);
  hipLaunchKernelGGL(k_final,    dim3(2048),   dim3(256), 0, stream, C, Q, ws, out);
}

// Round 6
// 329.444 us; speedup vs baseline: 1.3738x; 1.3738x over previous
//
#include <hip/hip_runtime.h>
#include <stdint.h>
#include <stddef.h>

#define NB  64
#define ND  256
#define NLC 1024
#define NLQ 128
#define INVKEEP (1.0f/0.9f)

// ---- workspace layout (float offsets) ----
#define OFF_SQ    0u            // NB*NLQ
#define OFF_RMAX  8192u         // NB*NLC  (row max of S)
#define OFF_RSUM  73728u        // NB*NLC  (RECIPROCAL row sum)
#define OFF_CMAX  139264u       // NB*NLQ  (col max)
#define OFF_CSUM  147456u       // NB*NLQ  (RECIPROCAL col sum)
#define OFF_S     155648u       // NB*NLC*NLQ (raw S)
#define OFF_M     8544256u      // 2*NB*ND*NLQ (split-K partial M)

typedef float f32x4  __attribute__((ext_vector_type(4)));
typedef short bf16x8 __attribute__((ext_vector_type(8)));

// bf16 helpers: RNE pack
__device__ __forceinline__ uint32_t f2bf(float x) {
  const uint32_t u = __float_as_uint(x);
  return (u + 0x7fffu + ((u >> 16) & 1u)) >> 16;
}

// ================= threefry2x32, key=(0,42); bits = o0^o1 (verified r2) =====
__device__ __forceinline__ void tf_round(uint32_t& a, uint32_t& b, const int r) {
  a += b;
  b = (b << r) | (b >> (32 - r));
  b ^= a;
}
__device__ __forceinline__ uint32_t threefry_xor(uint32_t x0, uint32_t x1) {
  const uint32_t ks0 = 0u, ks1 = 42u, ks2 = 0x1BD11BDAu ^ 0u ^ 42u;
  x0 += ks0; x1 += ks1;
  tf_round(x0,x1,13); tf_round(x0,x1,15); tf_round(x0,x1,26); tf_round(x0,x1,6);
  x0 += ks1; x1 += ks2 + 1u;
  tf_round(x0,x1,17); tf_round(x0,x1,29); tf_round(x0,x1,16); tf_round(x0,x1,24);
  x0 += ks2; x1 += ks0 + 2u;
  tf_round(x0,x1,13); tf_round(x0,x1,15); tf_round(x0,x1,26); tf_round(x0,x1,6);
  x0 += ks0; x1 += ks1 + 3u;
  tf_round(x0,x1,17); tf_round(x0,x1,29); tf_round(x0,x1,16); tf_round(x0,x1,24);
  x0 += ks1; x1 += ks2 + 4u;
  tf_round(x0,x1,13); tf_round(x0,x1,15); tf_round(x0,x1,26); tf_round(x0,x1,6);
  x0 += ks2; x1 += ks0 + 5u;
  return x0 ^ x1;
}

// ================= sq[b,j] = sum_d wq[d] * Q[b,d,j] ==========================
__global__ __launch_bounds__(128) void k_sq(const float* __restrict__ Q,
                                            const float* __restrict__ W,
                                            float* __restrict__ ws) {
  const int b = blockIdx.x;
  const int j = threadIdx.x;
  const float* wq = W + (size_t)b*768;
  const float* Qb = Q + (size_t)b*ND*NLQ;
  float acc = 0.0f;
  for (int d = 0; d < ND; ++d) acc = fmaf(wq[d], Qb[(size_t)d*NLQ + j], acc);
  ws[OFF_SQ + (size_t)b*NLQ + j] = acc;
}

// ========== S[b,i,j] = sum_d C[d,i]*(wm[d]*Q[d,j]+wc[d]) + sq[j] ============
__global__ __launch_bounds__(256) void k_s(const float* __restrict__ C,
                                           const float* __restrict__ Q,
                                           const float* __restrict__ W,
                                           float* __restrict__ ws) {
  __shared__ float Cs[32][64];
  __shared__ float Qs[32][128];
  __shared__ float wmS[256], wcS[256], sqS[128];
  const int b  = blockIdx.y;
  const int i0 = blockIdx.x * 64;
  const int t  = threadIdx.x;
  const int jg = t & 15;        // j = jg*8 .. +7
  const int ig = t >> 4;        // i = i0 + ig*4 .. +3
  wcS[t] = W[(size_t)b*768 + 256 + t];
  wmS[t] = W[(size_t)b*768 + 512 + t];
  if (t < 128) sqS[t] = ws[OFF_SQ + (size_t)b*NLQ + t];

  float acc[4][8];
  #pragma unroll
  for (int r = 0; r < 4; ++r)
    #pragma unroll
    for (int x = 0; x < 8; ++x) acc[r][x] = 0.0f;

  const float* Cb = C + (size_t)b*ND*NLC;
  const float* Qb = Q + (size_t)b*ND*NLQ;

  for (int d0 = 0; d0 < ND; d0 += 32) {
    __syncthreads();
    #pragma unroll
    for (int r = 0; r < 2; ++r) {
      const int f = r*256 + t;
      const int dk = f >> 4, i4 = f & 15;
      *(float4*)&Cs[dk][i4*4] = *(const float4*)&Cb[(size_t)(d0+dk)*NLC + i0 + i4*4];
    }
    #pragma unroll
    for (int r = 0; r < 4; ++r) {
      const int f = r*256 + t;
      const int dk = f >> 5, j4 = f & 31;
      const float4 qv = *(const float4*)&Qb[(size_t)(d0+dk)*NLQ + j4*4];
      const float wmv = wmS[d0+dk], wcv = wcS[d0+dk];
      float4 o;
      o.x = fmaf(wmv, qv.x, wcv);
      o.y = fmaf(wmv, qv.y, wcv);
      o.z = fmaf(wmv, qv.z, wcv);
      o.w = fmaf(wmv, qv.w, wcv);
      *(float4*)&Qs[dk][j4*4] = o;
    }
    __syncthreads();
    #pragma unroll
    for (int dk = 0; dk < 32; ++dk) {
      const float4 cq = *(const float4*)&Cs[dk][ig*4];
      const float4 q0 = *(const float4*)&Qs[dk][jg*8];
      const float4 q1 = *(const float4*)&Qs[dk][jg*8+4];
      const float cr[4] = {cq.x, cq.y, cq.z, cq.w};
      const float qv[8] = {q0.x,q0.y,q0.z,q0.w,q1.x,q1.y,q1.z,q1.w};
      #pragma unroll
      for (int r = 0; r < 4; ++r)
        #pragma unroll
        for (int x = 0; x < 8; ++x)
          acc[r][x] = fmaf(cr[r], qv[x], acc[r][x]);
    }
  }

  float sqv[8];
  #pragma unroll
  for (int x = 0; x < 8; ++x) sqv[x] = sqS[jg*8 + x];
  float* Sb = ws + OFF_S + ((size_t)b*NLC + (size_t)i0)*NLQ;
  #pragma unroll
  for (int r = 0; r < 4; ++r) {
    float sv[8];
    #pragma unroll
    for (int x = 0; x < 8; ++x) sv[x] = acc[r][x] + sqv[x];
    float m = sv[0];
    #pragma unroll
    for (int x = 1; x < 8; ++x) m = fmaxf(m, sv[x]);
    m = fmaxf(m, __shfl_xor(m, 1));
    m = fmaxf(m, __shfl_xor(m, 2));
    m = fmaxf(m, __shfl_xor(m, 4));
    m = fmaxf(m, __shfl_xor(m, 8));
    float s = 0.0f;
    #pragma unroll
    for (int x = 0; x < 8; ++x) s += __expf(sv[x] - m);
    s += __shfl_xor(s, 1);
    s += __shfl_xor(s, 2);
    s += __shfl_xor(s, 4);
    s += __shfl_xor(s, 8);
    const int row = ig*4 + r;
    *(float4*)&Sb[(size_t)row*NLQ + jg*8]     = make_float4(sv[0],sv[1],sv[2],sv[3]);
    *(float4*)&Sb[(size_t)row*NLQ + jg*8 + 4] = make_float4(sv[4],sv[5],sv[6],sv[7]);
    if (jg == 0) {
      ws[OFF_RMAX + (size_t)b*NLC + i0 + row] = m;
      ws[OFF_RSUM + (size_t)b*NLC + i0 + row] = 1.0f / s;
    }
  }
}

// ============ column softmax stats over i (axis=1): cmax, 1/csum ============
__global__ __launch_bounds__(256) void k_colstats(float* __restrict__ ws) {
  __shared__ float red[8][32];
  const int b  = blockIdx.y;
  const int jq = blockIdx.x;
  const int tx = threadIdx.x & 31;
  const int ty = threadIdx.x >> 5;
  const int j  = jq*32 + tx;
  const float* Sb = ws + OFF_S + (size_t)b*NLC*NLQ;
  float m = -3.0e38f;
  for (int ii = 0; ii < 128; ++ii)
    m = fmaxf(m, Sb[(size_t)(ty*128 + ii)*NLQ + j]);
  red[ty][tx] = m;
  __syncthreads();
  if (ty == 0) {
    #pragma unroll
    for (int y = 1; y < 8; ++y) m = fmaxf(m, red[y][tx]);
    red[0][tx] = m;
  }
  __syncthreads();
  const float cm = red[0][tx];
  __syncthreads();
  float s = 0.0f;
  for (int ii = 0; ii < 128; ++ii)
    s += __expf(Sb[(size_t)(ty*128 + ii)*NLQ + j] - cm);
  red[ty][tx] = s;
  __syncthreads();
  if (ty == 0) {
    #pragma unroll
    for (int y = 1; y < 8; ++y) s += red[y][tx];
    ws[OFF_CMAX + (size_t)b*NLQ + j] = cm;
    ws[OFF_CSUM + (size_t)b*NLQ + j] = 1.0f / s;
  }
}

// ======= M[b,d,j] = sum_k C[b,d,k] * S__[b,k,j]  (split-K=2, d-split=4) =====
__global__ __launch_bounds__(256) void k_m(const float* __restrict__ C,
                                           float* __restrict__ ws) {
  __shared__ float Ps[32][128];
  __shared__ float Csh[32][68];
  __shared__ float cmS[128], icS[128];
  const int n   = blockIdx.x;
  const int rr  = n & 7, qq = n >> 3;
  const int dq  = qq & 3;               // member: d quarter
  const int g   = (qq >> 2) * 8 + rr;   // group 0..127 = (ksp,b)
  const int b   = g & 63;
  const int ksp = g >> 6;
  const int t   = threadIdx.x;
  const int jg  = t & 15;
  const int dg  = t >> 4;
  if (t < 128) {
    cmS[t] = ws[OFF_CMAX + (size_t)b*NLQ + t];
    icS[t] = ws[OFF_CSUM + (size_t)b*NLQ + t];
  }
  float acc[4][8];
  #pragma unroll
  for (int r = 0; r < 4; ++r)
    #pragma unroll
    for (int x = 0; x < 8; ++x) acc[r][x] = 0.0f;

  const float* Cb = C + (size_t)b*ND*NLC + (size_t)dq*64*NLC;
  const float* Sb = ws + OFF_S + (size_t)b*NLC*NLQ;
  const int kbase = ksp * 512;

  for (int kt = 0; kt < 16; ++kt) {
    const int k0 = kbase + kt*32;
    __syncthreads();
    #pragma unroll
    for (int r = 0; r < 4; ++r) {
      const int f = r*256 + t;
      const int kk = f >> 5, j4 = f & 31;
      const float4 sv = *(const float4*)&Sb[(size_t)(k0+kk)*NLQ + j4*4];
      const int j = j4*4;
      float4 p;
      p.x = __expf(sv.x - cmS[j+0]) * icS[j+0];
      p.y = __expf(sv.y - cmS[j+1]) * icS[j+1];
      p.z = __expf(sv.z - cmS[j+2]) * icS[j+2];
      p.w = __expf(sv.w - cmS[j+3]) * icS[j+3];
      *(float4*)&Ps[kk][j4*4] = p;
    }
    #pragma unroll
    for (int r = 0; r < 2; ++r) {
      const int f = r*256 + t;
      const int kq = f & 7, dl = f >> 3;
      const float4 cv = *(const float4*)&Cb[(size_t)dl*NLC + k0 + kq*4];
      Csh[kq*4+0][dl] = cv.x;
      Csh[kq*4+1][dl] = cv.y;
      Csh[kq*4+2][dl] = cv.z;
      Csh[kq*4+3][dl] = cv.w;
    }
    __syncthreads();
    #pragma unroll
    for (int kk = 0; kk < 32; ++kk) {
      const float4 c4 = *(const float4*)&Csh[kk][dg*4];
      const float4 p0 = *(const float4*)&Ps[kk][jg*8];
      const float4 p1 = *(const float4*)&Ps[kk][jg*8+4];
      const float cr[4] = {c4.x,c4.y,c4.z,c4.w};
      const float pv[8] = {p0.x,p0.y,p0.z,p0.w,p1.x,p1.y,p1.z,p1.w};
      #pragma unroll
      for (int r = 0; r < 4; ++r)
        #pragma unroll
        for (int x = 0; x < 8; ++x)
          acc[r][x] = fmaf(cr[r], pv[x], acc[r][x]);
    }
  }
  float* Mp = ws + OFF_M + ((size_t)ksp*NB + b)*ND*NLQ + (size_t)dq*64*NLQ;
  #pragma unroll
  for (int r = 0; r < 4; ++r) {
    const int d = dg*4 + r;
    *(float4*)&Mp[(size_t)d*NLQ + jg*8]     = make_float4(acc[r][0],acc[r][1],acc[r][2],acc[r][3]);
    *(float4*)&Mp[(size_t)d*NLQ + jg*8 + 4] = make_float4(acc[r][4],acc[r][5],acc[r][6],acc[r][7]);
  }
}

// ==== final (MFMA): A = Q*S_^T, Bm = M*S_^T, out = [C, A, C*A, C*Bm] ========
// bf16 staging + MFMA as round 4/5. New epilogue: acc transposed through LDS
// (aliasing the dead staging buffers) so stores are FULL-LINE float4 — no
// fetch-on-write RMW. Threefry inline, d-loop ROLLED to fit L1I.
__global__ __launch_bounds__(256, 2) void k_final(const float* __restrict__ C,
                                                  const float* __restrict__ Q,
                                                  float* __restrict__ ws,
                                                  float* __restrict__ out) {
  __shared__ __align__(16) uint8_t smem[65536];
  ushort (*St)[128] = (ushort(*)[128])smem;            // [i][j] bf16, swizzled
  ushort (*Qt)[128] = (ushort(*)[128])(smem + 32768);  // [d][j] bf16, swizzled
  ushort (*Mt)[128] = (ushort(*)[128])(smem + 49152);  // [d][j] bf16 (M0+M1)
  float  (*At)[128] = (float (*)[128])smem;            // epilogue: A [d][i]
  float  (*Bt)[128] = (float (*)[128])(smem + 32768);  // epilogue: B [d][i]

  const int n  = blockIdx.x;
  const int rr = n & 7, qq = n >> 3;
  const int m  = qq & 3;                // member: d0 block
  const int g  = (qq >> 2) * 8 + rr;    // group 0..511 = (i0,b)
  const int b  = g & 63;
  const int i0 = (g >> 6) * 128;
  const int d0 = m * 64;
  const int t  = threadIdx.x;

  // --- stage S_ (row-softmax applied) as bf16 rows ---
  const float* Sb  = ws + OFF_S + ((size_t)b*NLC + (size_t)i0)*NLQ;
  const float* rmp = ws + OFF_RMAX + (size_t)b*NLC + i0;
  const float* irp = ws + OFF_RSUM + (size_t)b*NLC + i0;
  #pragma unroll
  for (int p = 0; p < 16; ++p) {
    const int f  = p*256 + t;
    const int j4 = f & 31;              // 4 consecutive j
    const int il = f >> 5;              // row 0..127
    const float4 sv = *(const float4*)&Sb[(size_t)il*NLQ + j4*4];
    const float rm = rmp[il], ir = irp[il];
    uint2 pk;
    pk.x = f2bf(__expf(sv.x - rm) * ir) | (f2bf(__expf(sv.y - rm) * ir) << 16);
    pk.y = f2bf(__expf(sv.z - rm) * ir) | (f2bf(__expf(sv.w - rm) * ir) << 16);
    *(uint2*)&St[il][(j4*4) ^ ((il & 7) << 3)] = pk;
  }
  // --- stage Q and M (=M0+M1) as bf16 rows ---
  const float* Qb  = Q + (size_t)b*ND*NLQ + (size_t)d0*NLQ;
  const float* M0p = ws + OFF_M + (size_t)b*ND*NLQ + (size_t)d0*NLQ;
  const float* M1p = M0p + (size_t)NB*ND*NLQ;
  #pragma unroll
  for (int p = 0; p < 8; ++p) {
    const int f  = p*256 + t;
    const int j4 = f & 31;
    const int dl = f >> 5;              // row 0..63
    const int col = (j4*4) ^ ((dl & 7) << 3);
    const float4 qv = *(const float4*)&Qb[(size_t)dl*NLQ + j4*4];
    uint2 pq;
    pq.x = f2bf(qv.x) | (f2bf(qv.y) << 16);
    pq.y = f2bf(qv.z) | (f2bf(qv.w) << 16);
    *(uint2*)&Qt[dl][col] = pq;
    const float4 m0 = *(const float4*)&M0p[(size_t)dl*NLQ + j4*4];
    const float4 m1 = *(const float4*)&M1p[(size_t)dl*NLQ + j4*4];
    uint2 pm;
    pm.x = f2bf(m0.x + m1.x) | (f2bf(m0.y + m1.y) << 16);
    pm.y = f2bf(m0.z + m1.z) | (f2bf(m0.w + m1.w) << 16);
    *(uint2*)&Mt[dl][col] = pm;
  }
  __syncthreads();

  // --- MFMA main loop: wave w owns d-rows [w*16, w*16+16) ---
  const int w  = t >> 6;
  const int l  = t & 63;
  const int lm = l & 15;                // 16-dim index (m for A, n for B/D)
  const int lk = (l >> 4) * 8;          // k sub-offset
  const int sw = (lm & 7) << 3;         // row-swizzle (row&7 == lm&7 everywhere)

  f32x4 accA[8], accB[8];
  #pragma unroll
  for (int f = 0; f < 8; ++f) { accA[f] = (f32x4)0.0f; accB[f] = (f32x4)0.0f; }

  #pragma unroll
  for (int ks = 0; ks < 4; ++ks) {
    const int koff = (ks*32 + lk) ^ sw;
    const bf16x8 qf = *(const bf16x8*)&Qt[w*16 + lm][koff];
    const bf16x8 mf = *(const bf16x8*)&Mt[w*16 + lm][koff];
    #pragma unroll
    for (int f = 0; f < 8; ++f) {
      const bf16x8 sf = *(const bf16x8*)&St[f*16 + lm][koff];
      accA[f] = __builtin_amdgcn_mfma_f32_16x16x32_bf16(qf, sf, accA[f], 0, 0, 0);
      accB[f] = __builtin_amdgcn_mfma_f32_16x16x32_bf16(mf, sf, accB[f], 0, 0, 0);
    }
  }
  __syncthreads();   // staging buffers dead; reuse as At/Bt

  // --- transpose acc to LDS [d][i] fp32, XOR swizzle (16B granule) ---
  // D frag: col(=i)=lane&15, row(=d)=(lane>>4)*4+reg
  const int dwl = w*16 + (l >> 4)*4;    // d-local base of this lane's rows
  #pragma unroll
  for (int f = 0; f < 8; ++f) {
    const int i = f*16 + lm;
    #pragma unroll
    for (int r = 0; r < 4; ++r) {
      const int dl = dwl + r;
      const int isw = i ^ ((dl & 7) << 2);
      At[dl][isw] = accA[f][r];
      Bt[dl][isw] = accB[f][r];
    }
  }
  __syncthreads();

  // --- full-line stores: lanes 0..31 cover i 0..127 contiguously ---
  const int il4 = (t & 31) * 4;         // i offset (float4)
  const int dg8 = t >> 5;               // 0..7
  const float* Cb = C + (size_t)b*ND*NLC;
  #pragma unroll 1                      // keep body small: fits L1I
  for (int dd = 0; dd < 8; ++dd) {
    const int dl = dd*8 + dg8;          // 0..63
    const int d  = d0 + dl;
    const int isw = il4 ^ ((dl & 7) << 2);
    const float4 a4 = *(const float4*)&At[dl][isw];
    const float4 b4 = *(const float4*)&Bt[dl][isw];
    const float4 c4 = *(const float4*)&Cb[(size_t)d*NLC + i0 + il4];
    const float av[4] = {a4.x, a4.y, a4.z, a4.w};
    const float bv[4] = {b4.x, b4.y, b4.z, b4.w};
    const float cv[4] = {c4.x, c4.y, c4.z, c4.w};
    #pragma unroll
    for (int s = 0; s < 4; ++s) {
      const uint32_t nb = ((((uint32_t)b << 10) + (uint32_t)(s*ND + d)) << 10)
                          + (uint32_t)(i0 + il4);
      float ov[4];
      #pragma unroll
      for (int e = 0; e < 4; ++e) {
        const uint32_t bits = threefry_xor(0u, nb + (uint32_t)e);
        const float u = __uint_as_float((bits >> 9) | 0x3f800000u) - 1.0f;
        float v;
        if (s == 0)      v = cv[e];
        else if (s == 1) v = av[e];
        else if (s == 2) v = cv[e] * av[e];
        else             v = cv[e] * bv[e];
        ov[e] = (u < 0.9f) ? v * INVKEEP : 0.0f;
      }
      *(float4*)&out[nb] = make_float4(ov[0], ov[1], ov[2], ov[3]);
    }
  }
}

extern "C" void kernel_launch(void* const* d_in, const int* in_sizes, int n_in,
                              void* d_out, int out_size, void* d_ws, size_t ws_size,
                              hipStream_t stream) {
  (void)in_sizes; (void)n_in; (void)out_size; (void)ws_size;
  const float* C = (const float*)d_in[0];
  const float* Q = (const float*)d_in[1];
  const float* W = (const float*)d_in[2];
  float* out = (float*)d_out;
  float* ws  = (float*)d_ws;

  hipLaunchKernelGGL(k_sq,       dim3(NB),     dim3(128), 0, stream, Q, W, ws);
  hipLaunchKernelGGL(k_s,        dim3(16, NB), dim3(256), 0, stream, C, Q, W, ws);
  hipLaunchKernelGGL(k_colstats, dim3(4, NB),  dim3(256), 0, stream, ws);
  hipLaunchKernelGGL(k_m,        dim3(512),    dim3(256), 0, stream, C, ws);
  hipLaunchKernelGGL(k_final,    dim3(2048),   dim3(256), 0, stream, C, Q, ws, out);
}

// Round 7
// 314.336 us; speedup vs baseline: 1.4398x; 1.0481x over previous
//
#include <hip/hip_runtime.h>
#include <stdint.h>
#include <stddef.h>

#define NB  64
#define ND  256
#define NLC 1024
#define NLQ 128
#define INVKEEP (1.0f/0.9f)

// ---- workspace layout (float offsets) ----
#define OFF_SQ    0u            // NB*NLQ
#define OFF_RMAX  8192u         // NB*NLC  (row max of S)
#define OFF_RSUM  73728u        // NB*NLC  (RECIPROCAL row sum)
#define OFF_CMAX  139264u       // NB*NLQ  (col max)
#define OFF_CSUM  147456u       // NB*NLQ  (RECIPROCAL col sum)
#define OFF_S     155648u       // NB*NLC*NLQ (raw S)
#define OFF_M     8544256u      // 2*NB*ND*NLQ bf16 partials (region fits)

typedef float f32x4  __attribute__((ext_vector_type(4)));
typedef short bf16x8 __attribute__((ext_vector_type(8)));

// bf16 helpers: RNE pack; unpack packed pair (lo = even index)
__device__ __forceinline__ uint32_t f2bf(float x) {
  const uint32_t u = __float_as_uint(x);
  return (u + 0x7fffu + ((u >> 16) & 1u)) >> 16;
}
__device__ __forceinline__ float bflo(uint32_t p) { return __uint_as_float(p << 16); }
__device__ __forceinline__ float bfhi(uint32_t p) { return __uint_as_float(p & 0xffff0000u); }

// ================= threefry2x32, key=(0,42); bits = o0^o1 (verified r2) =====
__device__ __forceinline__ void tf_round(uint32_t& a, uint32_t& b, const int r) {
  a += b;
  b = (b << r) | (b >> (32 - r));
  b ^= a;
}
__device__ __forceinline__ uint32_t threefry_xor(uint32_t x0, uint32_t x1) {
  const uint32_t ks0 = 0u, ks1 = 42u, ks2 = 0x1BD11BDAu ^ 0u ^ 42u;
  x0 += ks0; x1 += ks1;
  tf_round(x0,x1,13); tf_round(x0,x1,15); tf_round(x0,x1,26); tf_round(x0,x1,6);
  x0 += ks1; x1 += ks2 + 1u;
  tf_round(x0,x1,17); tf_round(x0,x1,29); tf_round(x0,x1,16); tf_round(x0,x1,24);
  x0 += ks2; x1 += ks0 + 2u;
  tf_round(x0,x1,13); tf_round(x0,x1,15); tf_round(x0,x1,26); tf_round(x0,x1,6);
  x0 += ks0; x1 += ks1 + 3u;
  tf_round(x0,x1,17); tf_round(x0,x1,29); tf_round(x0,x1,16); tf_round(x0,x1,24);
  x0 += ks1; x1 += ks2 + 4u;
  tf_round(x0,x1,13); tf_round(x0,x1,15); tf_round(x0,x1,26); tf_round(x0,x1,6);
  x0 += ks2; x1 += ks0 + 5u;
  return x0 ^ x1;
}

// ================= sq[b,j] = sum_d wq[d] * Q[b,d,j] ==========================
__global__ __launch_bounds__(128) void k_sq(const float* __restrict__ Q,
                                            const float* __restrict__ W,
                                            float* __restrict__ ws) {
  const int b = blockIdx.x;
  const int j = threadIdx.x;
  const float* wq = W + (size_t)b*768;
  const float* Qb = Q + (size_t)b*ND*NLQ;
  float acc = 0.0f;
  for (int d = 0; d < ND; ++d) acc = fmaf(wq[d], Qb[(size_t)d*NLQ + j], acc);
  ws[OFF_SQ + (size_t)b*NLQ + j] = acc;
}

// ========== S[b,i,j] = sum_d C[d,i]*(wm[d]*Q[d,j]+wc[d]) + sq[j] ============
__global__ __launch_bounds__(256) void k_s(const float* __restrict__ C,
                                           const float* __restrict__ Q,
                                           const float* __restrict__ W,
                                           float* __restrict__ ws) {
  __shared__ float Cs[32][64];
  __shared__ float Qs[32][128];
  __shared__ float wmS[256], wcS[256], sqS[128];
  const int b  = blockIdx.y;
  const int i0 = blockIdx.x * 64;
  const int t  = threadIdx.x;
  const int jg = t & 15;        // j = jg*8 .. +7
  const int ig = t >> 4;        // i = i0 + ig*4 .. +3
  wcS[t] = W[(size_t)b*768 + 256 + t];
  wmS[t] = W[(size_t)b*768 + 512 + t];
  if (t < 128) sqS[t] = ws[OFF_SQ + (size_t)b*NLQ + t];

  float acc[4][8];
  #pragma unroll
  for (int r = 0; r < 4; ++r)
    #pragma unroll
    for (int x = 0; x < 8; ++x) acc[r][x] = 0.0f;

  const float* Cb = C + (size_t)b*ND*NLC;
  const float* Qb = Q + (size_t)b*ND*NLQ;

  for (int d0 = 0; d0 < ND; d0 += 32) {
    __syncthreads();
    #pragma unroll
    for (int r = 0; r < 2; ++r) {
      const int f = r*256 + t;
      const int dk = f >> 4, i4 = f & 15;
      *(float4*)&Cs[dk][i4*4] = *(const float4*)&Cb[(size_t)(d0+dk)*NLC + i0 + i4*4];
    }
    #pragma unroll
    for (int r = 0; r < 4; ++r) {
      const int f = r*256 + t;
      const int dk = f >> 5, j4 = f & 31;
      const float4 qv = *(const float4*)&Qb[(size_t)(d0+dk)*NLQ + j4*4];
      const float wmv = wmS[d0+dk], wcv = wcS[d0+dk];
      float4 o;
      o.x = fmaf(wmv, qv.x, wcv);
      o.y = fmaf(wmv, qv.y, wcv);
      o.z = fmaf(wmv, qv.z, wcv);
      o.w = fmaf(wmv, qv.w, wcv);
      *(float4*)&Qs[dk][j4*4] = o;
    }
    __syncthreads();
    #pragma unroll
    for (int dk = 0; dk < 32; ++dk) {
      const float4 cq = *(const float4*)&Cs[dk][ig*4];
      const float4 q0 = *(const float4*)&Qs[dk][jg*8];
      const float4 q1 = *(const float4*)&Qs[dk][jg*8+4];
      const float cr[4] = {cq.x, cq.y, cq.z, cq.w};
      const float qv[8] = {q0.x,q0.y,q0.z,q0.w,q1.x,q1.y,q1.z,q1.w};
      #pragma unroll
      for (int r = 0; r < 4; ++r)
        #pragma unroll
        for (int x = 0; x < 8; ++x)
          acc[r][x] = fmaf(cr[r], qv[x], acc[r][x]);
    }
  }

  float sqv[8];
  #pragma unroll
  for (int x = 0; x < 8; ++x) sqv[x] = sqS[jg*8 + x];
  float* Sb = ws + OFF_S + ((size_t)b*NLC + (size_t)i0)*NLQ;
  #pragma unroll
  for (int r = 0; r < 4; ++r) {
    float sv[8];
    #pragma unroll
    for (int x = 0; x < 8; ++x) sv[x] = acc[r][x] + sqv[x];
    float m = sv[0];
    #pragma unroll
    for (int x = 1; x < 8; ++x) m = fmaxf(m, sv[x]);
    m = fmaxf(m, __shfl_xor(m, 1));
    m = fmaxf(m, __shfl_xor(m, 2));
    m = fmaxf(m, __shfl_xor(m, 4));
    m = fmaxf(m, __shfl_xor(m, 8));
    float s = 0.0f;
    #pragma unroll
    for (int x = 0; x < 8; ++x) s += __expf(sv[x] - m);
    s += __shfl_xor(s, 1);
    s += __shfl_xor(s, 2);
    s += __shfl_xor(s, 4);
    s += __shfl_xor(s, 8);
    const int row = ig*4 + r;
    *(float4*)&Sb[(size_t)row*NLQ + jg*8]     = make_float4(sv[0],sv[1],sv[2],sv[3]);
    *(float4*)&Sb[(size_t)row*NLQ + jg*8 + 4] = make_float4(sv[4],sv[5],sv[6],sv[7]);
    if (jg == 0) {
      ws[OFF_RMAX + (size_t)b*NLC + i0 + row] = m;
      ws[OFF_RSUM + (size_t)b*NLC + i0 + row] = 1.0f / s;
    }
  }
}

// ==== column softmax stats over i (axis=1): SINGLE-PASS online (m, s) ======
__global__ __launch_bounds__(256) void k_colstats(float* __restrict__ ws) {
  __shared__ float redm[8][32], reds[8][32];
  const int b  = blockIdx.y;
  const int jq = blockIdx.x;
  const int tx = threadIdx.x & 31;
  const int ty = threadIdx.x >> 5;
  const int j  = jq*32 + tx;
  const float* Sb = ws + OFF_S + (size_t)b*NLC*NLQ;
  float m = -3.0e38f, s = 0.0f;
  for (int ii = 0; ii < 128; ++ii) {
    const float v = Sb[(size_t)(ty*128 + ii)*NLQ + j];
    const float nm = fmaxf(m, v);
    s = s * __expf(m - nm) + __expf(v - nm);
    m = nm;
  }
  redm[ty][tx] = m; reds[ty][tx] = s;
  __syncthreads();
  if (ty == 0) {
    #pragma unroll
    for (int y = 1; y < 8; ++y) {
      const float m2 = redm[y][tx], s2 = reds[y][tx];
      const float nm = fmaxf(m, m2);
      s = s * __expf(m - nm) + s2 * __expf(m2 - nm);
      m = nm;
    }
    ws[OFF_CMAX + (size_t)b*NLQ + j] = m;
    ws[OFF_CSUM + (size_t)b*NLQ + j] = 1.0f / s;
  }
}

// ======= M[b,d,j] = sum_k C[b,d,k] * S__[b,k,j]  (split-K=2, d-split=4) =====
// bf16 partial outputs (k_final rounds to bf16 anyway). XCD-grouped.
__global__ __launch_bounds__(256) void k_m(const float* __restrict__ C,
                                           float* __restrict__ ws) {
  __shared__ float Ps[32][128];
  __shared__ float Csh[32][68];
  __shared__ float cmS[128], icS[128];
  const int n   = blockIdx.x;
  const int rr  = n & 7, qq = n >> 3;
  const int dq  = qq & 3;               // member: d quarter
  const int g   = (qq >> 2) * 8 + rr;   // group 0..127 = (ksp,b)
  const int b   = g & 63;
  const int ksp = g >> 6;
  const int t   = threadIdx.x;
  const int jg  = t & 15;
  const int dg  = t >> 4;
  if (t < 128) {
    cmS[t] = ws[OFF_CMAX + (size_t)b*NLQ + t];
    icS[t] = ws[OFF_CSUM + (size_t)b*NLQ + t];
  }
  float acc[4][8];
  #pragma unroll
  for (int r = 0; r < 4; ++r)
    #pragma unroll
    for (int x = 0; x < 8; ++x) acc[r][x] = 0.0f;

  const float* Cb = C + (size_t)b*ND*NLC + (size_t)dq*64*NLC;
  const float* Sb = ws + OFF_S + (size_t)b*NLC*NLQ;
  const int kbase = ksp * 512;

  for (int kt = 0; kt < 16; ++kt) {
    const int k0 = kbase + kt*32;
    __syncthreads();
    #pragma unroll
    for (int r = 0; r < 4; ++r) {
      const int f = r*256 + t;
      const int kk = f >> 5, j4 = f & 31;
      const float4 sv = *(const float4*)&Sb[(size_t)(k0+kk)*NLQ + j4*4];
      const int j = j4*4;
      float4 p;
      p.x = __expf(sv.x - cmS[j+0]) * icS[j+0];
      p.y = __expf(sv.y - cmS[j+1]) * icS[j+1];
      p.z = __expf(sv.z - cmS[j+2]) * icS[j+2];
      p.w = __expf(sv.w - cmS[j+3]) * icS[j+3];
      *(float4*)&Ps[kk][j4*4] = p;
    }
    #pragma unroll
    for (int r = 0; r < 2; ++r) {
      const int f = r*256 + t;
      const int kq = f & 7, dl = f >> 3;
      const float4 cv = *(const float4*)&Cb[(size_t)dl*NLC + k0 + kq*4];
      Csh[kq*4+0][dl] = cv.x;
      Csh[kq*4+1][dl] = cv.y;
      Csh[kq*4+2][dl] = cv.z;
      Csh[kq*4+3][dl] = cv.w;
    }
    __syncthreads();
    #pragma unroll
    for (int kk = 0; kk < 32; ++kk) {
      const float4 c4 = *(const float4*)&Csh[kk][dg*4];
      const float4 p0 = *(const float4*)&Ps[kk][jg*8];
      const float4 p1 = *(const float4*)&Ps[kk][jg*8+4];
      const float cr[4] = {c4.x,c4.y,c4.z,c4.w};
      const float pv[8] = {p0.x,p0.y,p0.z,p0.w,p1.x,p1.y,p1.z,p1.w};
      #pragma unroll
      for (int r = 0; r < 4; ++r)
        #pragma unroll
        for (int x = 0; x < 8; ++x)
          acc[r][x] = fmaf(cr[r], pv[x], acc[r][x]);
    }
  }
  ushort* Mp = (ushort*)(ws + OFF_M)
             + ((size_t)ksp*NB + b)*ND*NLQ + (size_t)dq*64*NLQ;
  #pragma unroll
  for (int r = 0; r < 4; ++r) {
    const int d = dg*4 + r;
    uint4 pk;
    pk.x = f2bf(acc[r][0]) | (f2bf(acc[r][1]) << 16);
    pk.y = f2bf(acc[r][2]) | (f2bf(acc[r][3]) << 16);
    pk.z = f2bf(acc[r][4]) | (f2bf(acc[r][5]) << 16);
    pk.w = f2bf(acc[r][6]) | (f2bf(acc[r][7]) << 16);
    *(uint4*)&Mp[(size_t)d*NLQ + jg*8] = pk;
  }
}

// ==== final (MFMA): A = Q*S_^T, Bm = M*S_^T, out = [C, A, C*A, C*Bm] ========
// d-tile 32 -> LDS 48KB -> 3 blocks/CU (12 waves/CU) to feed the VALU with
// the inline threefry. 8-member XCD groups = 8 d-blocks sharing one S-tile.
__global__ __launch_bounds__(256, 3) void k_final(const float* __restrict__ C,
                                                  const float* __restrict__ Q,
                                                  float* __restrict__ ws,
                                                  float* __restrict__ out) {
  __shared__ __align__(16) uint8_t smem[49152];
  ushort (*St)[128] = (ushort(*)[128])smem;            // [i 128][j 128] 32KB
  ushort (*Qt)[128] = (ushort(*)[128])(smem + 32768);  // [d 32][j 128]  8KB
  ushort (*Mt)[128] = (ushort(*)[128])(smem + 40960);  // [d 32][j 128]  8KB
  float  (*At)[128] = (float (*)[128])smem;            // epilogue [d 32][i 128]
  float  (*Bt)[128] = (float (*)[128])(smem + 16384);

  const int n  = blockIdx.x;
  const int r8 = n & 7, q = n >> 3;
  const int m  = q & 7;                 // member: d0 block (8 of 32 rows)
  const int g  = (q >> 3) * 8 + r8;     // group 0..511 = (i0,b), one XCD
  const int b  = g & 63;
  const int i0 = (g >> 6) * 128;
  const int d0 = m * 32;
  const int t  = threadIdx.x;

  // --- stage S_ (row-softmax applied) as bf16 rows ---
  const float* Sb  = ws + OFF_S + ((size_t)b*NLC + (size_t)i0)*NLQ;
  const float* rmp = ws + OFF_RMAX + (size_t)b*NLC + i0;
  const float* irp = ws + OFF_RSUM + (size_t)b*NLC + i0;
  #pragma unroll
  for (int p = 0; p < 16; ++p) {
    const int f  = p*256 + t;
    const int j4 = f & 31;
    const int il = f >> 5;              // row 0..127
    const float4 sv = *(const float4*)&Sb[(size_t)il*NLQ + j4*4];
    const float rm = rmp[il], ir = irp[il];
    uint2 pk;
    pk.x = f2bf(__expf(sv.x - rm) * ir) | (f2bf(__expf(sv.y - rm) * ir) << 16);
    pk.y = f2bf(__expf(sv.z - rm) * ir) | (f2bf(__expf(sv.w - rm) * ir) << 16);
    *(uint2*)&St[il][(j4*4) ^ ((il & 7) << 3)] = pk;
  }
  // --- stage Q (fp32->bf16) and M (=M0+M1, bf16 partials) ---
  const float*  Qb  = Q + (size_t)b*ND*NLQ + (size_t)d0*NLQ;
  const ushort* M0p = (const ushort*)(ws + OFF_M)
                    + (size_t)b*ND*NLQ + (size_t)d0*NLQ;
  const ushort* M1p = M0p + (size_t)NB*ND*NLQ;
  #pragma unroll
  for (int p = 0; p < 4; ++p) {
    const int f  = p*256 + t;
    const int j4 = f & 31;
    const int dl = f >> 5;              // row 0..31
    const int col = (j4*4) ^ ((dl & 7) << 3);
    const float4 qv = *(const float4*)&Qb[(size_t)dl*NLQ + j4*4];
    uint2 pq;
    pq.x = f2bf(qv.x) | (f2bf(qv.y) << 16);
    pq.y = f2bf(qv.z) | (f2bf(qv.w) << 16);
    *(uint2*)&Qt[dl][col] = pq;
    const uint2 u0 = *(const uint2*)&M0p[(size_t)dl*NLQ + j4*4];
    const uint2 u1 = *(const uint2*)&M1p[(size_t)dl*NLQ + j4*4];
    uint2 pm;
    pm.x = f2bf(bflo(u0.x) + bflo(u1.x)) | (f2bf(bfhi(u0.x) + bfhi(u1.x)) << 16);
    pm.y = f2bf(bflo(u0.y) + bflo(u1.y)) | (f2bf(bfhi(u0.y) + bfhi(u1.y)) << 16);
    *(uint2*)&Mt[dl][col] = pm;
  }
  __syncthreads();

  // --- MFMA: wave (wd=w&1, wi=w>>1): d-strip wd*16, i-frags wi*4..+3 ---
  const int w  = t >> 6;
  const int wd = w & 1, wi = w >> 1;
  const int l  = t & 63;
  const int lm = l & 15;
  const int lk = (l >> 4) * 8;
  const int sw = (lm & 7) << 3;

  f32x4 accA[4], accB[4];
  #pragma unroll
  for (int f = 0; f < 4; ++f) { accA[f] = (f32x4)0.0f; accB[f] = (f32x4)0.0f; }

  #pragma unroll
  for (int ks = 0; ks < 4; ++ks) {
    const int koff = (ks*32 + lk) ^ sw;
    const bf16x8 qf = *(const bf16x8*)&Qt[wd*16 + lm][koff];
    const bf16x8 mf = *(const bf16x8*)&Mt[wd*16 + lm][koff];
    #pragma unroll
    for (int f = 0; f < 4; ++f) {
      const bf16x8 sf = *(const bf16x8*)&St[(wi*4 + f)*16 + lm][koff];
      accA[f] = __builtin_amdgcn_mfma_f32_16x16x32_bf16(qf, sf, accA[f], 0, 0, 0);
      accB[f] = __builtin_amdgcn_mfma_f32_16x16x32_bf16(mf, sf, accB[f], 0, 0, 0);
    }
  }
  __syncthreads();   // staging buffers dead; reuse as At/Bt

  // --- transpose acc to LDS [d][i] fp32, XOR swizzle (16B granule) ---
  const int dwl = wd*16 + (l >> 4)*4;
  #pragma unroll
  for (int f = 0; f < 4; ++f) {
    const int i = (wi*4 + f)*16 + lm;
    #pragma unroll
    for (int r = 0; r < 4; ++r) {
      const int dl = dwl + r;
      const int isw = i ^ ((dl & 7) << 2);
      At[dl][isw] = accA[f][r];
      Bt[dl][isw] = accB[f][r];
    }
  }
  __syncthreads();

  // --- full-line stores: 32 lanes cover i 0..127 contiguously ---
  const int il4 = (t & 31) * 4;
  const int dg8 = t >> 5;               // 0..7
  const float* Cb = C + (size_t)b*ND*NLC;
  #pragma unroll 1                      // keep body small: fits L1I
  for (int dd = 0; dd < 4; ++dd) {
    const int dl = dd*8 + dg8;          // 0..31
    const int d  = d0 + dl;
    const int isw = il4 ^ ((dl & 7) << 2);
    const float4 a4 = *(const float4*)&At[dl][isw];
    const float4 b4 = *(const float4*)&Bt[dl][isw];
    const float4 c4 = *(const float4*)&Cb[(size_t)d*NLC + i0 + il4];
    const float av[4] = {a4.x, a4.y, a4.z, a4.w};
    const float bv[4] = {b4.x, b4.y, b4.z, b4.w};
    const float cv[4] = {c4.x, c4.y, c4.z, c4.w};
    #pragma unroll
    for (int s = 0; s < 4; ++s) {
      const uint32_t nb = ((((uint32_t)b << 10) + (uint32_t)(s*ND + d)) << 10)
                          + (uint32_t)(i0 + il4);
      float ov[4];
      #pragma unroll
      for (int e = 0; e < 4; ++e) {
        const uint32_t bits = threefry_xor(0u, nb + (uint32_t)e);
        const float u = __uint_as_float((bits >> 9) | 0x3f800000u) - 1.0f;
        float v;
        if (s == 0)      v = cv[e];
        else if (s == 1) v = av[e];
        else if (s == 2) v = cv[e] * av[e];
        else             v = cv[e] * bv[e];
        ov[e] = (u < 0.9f) ? v * INVKEEP : 0.0f;
      }
      *(float4*)&out[nb] = make_float4(ov[0], ov[1], ov[2], ov[3]);
    }
  }
}

extern "C" void kernel_launch(void* const* d_in, const int* in_sizes, int n_in,
                              void* d_out, int out_size, void* d_ws, size_t ws_size,
                              hipStream_t stream) {
  (void)in_sizes; (void)n_in; (void)out_size; (void)ws_size;
  const float* C = (const float*)d_in[0];
  const float* Q = (const float*)d_in[1];
  const float* W = (const float*)d_in[2];
  float* out = (float*)d_out;
  float* ws  = (float*)d_ws;

  hipLaunchKernelGGL(k_sq,       dim3(NB),     dim3(128), 0, stream, Q, W, ws);
  hipLaunchKernelGGL(k_s,        dim3(16, NB), dim3(256), 0, stream, C, Q, W, ws);
  hipLaunchKernelGGL(k_colstats, dim3(4, NB),  dim3(256), 0, stream, ws);
  hipLaunchKernelGGL(k_m,        dim3(512),    dim3(256), 0, stream, C, ws);
  hipLaunchKernelGGL(k_final,    dim3(4096),   dim3(256), 0, stream, C, Q, ws, out);
}

// Round 8
// 250.229 us; speedup vs baseline: 1.8087x; 1.2562x over previous
//
#include <hip/hip_runtime.h>
#include <stdint.h>
#include <stddef.h>

#define NB  64
#define ND  256
#define NLC 1024
#define NLQ 128
#define INVKEEP (1.0f/0.9f)

// ---- workspace layout (float offsets) ----
#define OFF_SQ    0u            // NB*NLQ
#define OFF_RMAX  8192u         // NB*NLC  (row max of S)
#define OFF_RSUM  73728u        // NB*NLC  (RECIPROCAL row sum)
#define OFF_CMAX  139264u       // NB*NLQ  (col max)
#define OFF_CSUM  147456u       // NB*NLQ  (RECIPROCAL col sum)
#define OFF_S     155648u       // NB*NLC*NLQ (raw S)
#define OFF_M     8544256u      // 2*NB*ND*NLQ bf16 partials

typedef float f32x4  __attribute__((ext_vector_type(4)));
typedef short bf16x8 __attribute__((ext_vector_type(8)));

// bf16 helpers
__device__ __forceinline__ uint32_t f2bf(float x) {
  const uint32_t u = __float_as_uint(x);
  return (u + 0x7fffu + ((u >> 16) & 1u)) >> 16;
}
__device__ __forceinline__ float bflo(uint32_t p) { return __uint_as_float(p << 16); }
__device__ __forceinline__ float bfhi(uint32_t p) { return __uint_as_float(p & 0xffff0000u); }
// packed f32x2 -> bf16x2 (lo = first arg), HW RNE
__device__ __forceinline__ uint32_t cvtpk(float lo, float hi) {
  uint32_t r;
  asm("v_cvt_pk_bf16_f32 %0, %1, %2" : "=v"(r) : "v"(lo), "v"(hi));
  return r;
}

// ================= threefry2x32, key=(0,42); bits = o0^o1 (verified r2) =====
__device__ __forceinline__ void tf_round(uint32_t& a, uint32_t& b, const int r) {
  a += b;
  b = (b << r) | (b >> (32 - r));
  b ^= a;
}
__device__ __forceinline__ uint32_t threefry_xor(uint32_t x0, uint32_t x1) {
  const uint32_t ks0 = 0u, ks1 = 42u, ks2 = 0x1BD11BDAu ^ 0u ^ 42u;
  x0 += ks0; x1 += ks1;
  tf_round(x0,x1,13); tf_round(x0,x1,15); tf_round(x0,x1,26); tf_round(x0,x1,6);
  x0 += ks1; x1 += ks2 + 1u;
  tf_round(x0,x1,17); tf_round(x0,x1,29); tf_round(x0,x1,16); tf_round(x0,x1,24);
  x0 += ks2; x1 += ks0 + 2u;
  tf_round(x0,x1,13); tf_round(x0,x1,15); tf_round(x0,x1,26); tf_round(x0,x1,6);
  x0 += ks0; x1 += ks1 + 3u;
  tf_round(x0,x1,17); tf_round(x0,x1,29); tf_round(x0,x1,16); tf_round(x0,x1,24);
  x0 += ks1; x1 += ks2 + 4u;
  tf_round(x0,x1,13); tf_round(x0,x1,15); tf_round(x0,x1,26); tf_round(x0,x1,6);
  x0 += ks2; x1 += ks0 + 5u;
  return x0 ^ x1;
}

// ================= sq[b,j] = sum_d wq[d] * Q[b,d,j] ==========================
__global__ __launch_bounds__(128) void k_sq(const float* __restrict__ Q,
                                            const float* __restrict__ W,
                                            float* __restrict__ ws) {
  const int b = blockIdx.x;
  const int j = threadIdx.x;
  const float* wq = W + (size_t)b*768;
  const float* Qb = Q + (size_t)b*ND*NLQ;
  float acc = 0.0f;
  for (int d = 0; d < ND; ++d) acc = fmaf(wq[d], Qb[(size_t)d*NLQ + j], acc);
  ws[OFF_SQ + (size_t)b*NLQ + j] = acc;
}

// ===== S (MFMA): S[i,j] = sum_d C[d,i]*Q'[d,j] + sq[j], fused row stats =====
// Both operands are d-major -> stage fp32 in padded LDS; frags built with
// conflict-free column reads (lane stride 1) + v_cvt_pk_bf16_f32.
// i-tile 128 x j 128, K=256. Grid 512 XCD-grouped (8 i-tiles share Q_b in L2).
__global__ __launch_bounds__(256) void k_s(const float* __restrict__ C,
                                           const float* __restrict__ Q,
                                           const float* __restrict__ W,
                                           float* __restrict__ ws) {
  __shared__ float Cs[32][129];     // [d][i] fp32, padded
  __shared__ float Qs[32][129];     // [d][j] fp32 (Q'=wm*Q+wc), padded
  __shared__ float wmS[256], wcS[256], sqS[128];
  const int n  = blockIdx.x;
  const int rr = n & 7, qq = n >> 3;
  const int it = qq & 7;                 // member: i-tile
  const int b  = (qq >> 3) * 8 + rr;     // group: batch
  const int i0 = it * 128;
  const int t  = threadIdx.x;
  wcS[t] = W[(size_t)b*768 + 256 + t];
  wmS[t] = W[(size_t)b*768 + 512 + t];
  if (t < 128) sqS[t] = ws[OFF_SQ + (size_t)b*NLQ + t];

  const float* Cb = C + (size_t)b*ND*NLC;
  const float* Qb = Q + (size_t)b*ND*NLQ;
  const int l  = t & 63, w = t >> 6;
  const int lm = l & 15, lg = l >> 4;

  f32x4 acc[2][8];
  #pragma unroll
  for (int mg = 0; mg < 2; ++mg)
    #pragma unroll
    for (int nf = 0; nf < 8; ++nf) acc[mg][nf] = (f32x4)0.0f;

  for (int d0 = 0; d0 < ND; d0 += 32) {
    __syncthreads();
    #pragma unroll
    for (int p = 0; p < 4; ++p) {        // stage C and Q' tiles (coalesced)
      const int f  = p*256 + t;
      const int dk = f >> 5, x4 = f & 31;
      *(float4*)&Cs[dk][x4*4] = *(const float4*)&Cb[(size_t)(d0+dk)*NLC + i0 + x4*4];
      const float4 qv = *(const float4*)&Qb[(size_t)(d0+dk)*NLQ + x4*4];
      const float wmv = wmS[d0+dk], wcv = wcS[d0+dk];
      float4 o;
      o.x = fmaf(wmv, qv.x, wcv);
      o.y = fmaf(wmv, qv.y, wcv);
      o.z = fmaf(wmv, qv.z, wcv);
      o.w = fmaf(wmv, qv.w, wcv);
      *(float4*)&Qs[dk][x4*4] = o;
    }
    __syncthreads();
    // B-frags (Q'): column reads, lane j = nf*16+lm
    bf16x8 bq[8];
    #pragma unroll
    for (int nf = 0; nf < 8; ++nf) {
      const int j = nf*16 + lm;
      union { uint32_t u[4]; bf16x8 v; } cc;
      #pragma unroll
      for (int kk = 0; kk < 4; ++kk)
        cc.u[kk] = cvtpk(Qs[lg*8 + kk*2][j], Qs[lg*8 + kk*2 + 1][j]);
      bq[nf] = cc.v;
    }
    #pragma unroll
    for (int mg = 0; mg < 2; ++mg) {
      const int i = w*32 + mg*16 + lm;
      union { uint32_t u[4]; bf16x8 v; } ca;
      #pragma unroll
      for (int kk = 0; kk < 4; ++kk)
        ca.u[kk] = cvtpk(Cs[lg*8 + kk*2][i], Cs[lg*8 + kk*2 + 1][i]);
      #pragma unroll
      for (int nf = 0; nf < 8; ++nf)
        acc[mg][nf] = __builtin_amdgcn_mfma_f32_16x16x32_bf16(ca.v, bq[nf], acc[mg][nf], 0, 0, 0);
    }
  }

  // epilogue: +sq, row stats (16-lane groups own rows), store raw S fp32
  float sqv[8];
  #pragma unroll
  for (int nf = 0; nf < 8; ++nf) sqv[nf] = sqS[nf*16 + lm];
  float* Sb = ws + OFF_S + ((size_t)b*NLC + (size_t)i0)*NLQ;
  #pragma unroll
  for (int mg = 0; mg < 2; ++mg) {
    #pragma unroll
    for (int r = 0; r < 4; ++r) {
      const int row = w*32 + mg*16 + lg*4 + r;   // i within tile
      float sv[8];
      #pragma unroll
      for (int nf = 0; nf < 8; ++nf) sv[nf] = acc[mg][nf][r] + sqv[nf];
      float mx = sv[0];
      #pragma unroll
      for (int nf = 1; nf < 8; ++nf) mx = fmaxf(mx, sv[nf]);
      mx = fmaxf(mx, __shfl_xor(mx, 1));
      mx = fmaxf(mx, __shfl_xor(mx, 2));
      mx = fmaxf(mx, __shfl_xor(mx, 4));
      mx = fmaxf(mx, __shfl_xor(mx, 8));
      float sm = 0.0f;
      #pragma unroll
      for (int nf = 0; nf < 8; ++nf) sm += __expf(sv[nf] - mx);
      sm += __shfl_xor(sm, 1);
      sm += __shfl_xor(sm, 2);
      sm += __shfl_xor(sm, 4);
      sm += __shfl_xor(sm, 8);
      #pragma unroll
      for (int nf = 0; nf < 8; ++nf)
        Sb[(size_t)row*NLQ + nf*16 + lm] = sv[nf];
      if (lm == 0) {
        ws[OFF_RMAX + (size_t)b*NLC + i0 + row] = mx;
        ws[OFF_RSUM + (size_t)b*NLC + i0 + row] = 1.0f / sm;
      }
    }
  }
}

// ==== column softmax stats over i (axis=1): SINGLE-PASS online (m, s) ======
__global__ __launch_bounds__(256) void k_colstats(float* __restrict__ ws) {
  __shared__ float redm[8][32], reds[8][32];
  const int b  = blockIdx.y;
  const int jq = blockIdx.x;
  const int tx = threadIdx.x & 31;
  const int ty = threadIdx.x >> 5;
  const int j  = jq*32 + tx;
  const float* Sb = ws + OFF_S + (size_t)b*NLC*NLQ;
  float m = -3.0e38f, s = 0.0f;
  for (int ii = 0; ii < 128; ++ii) {
    const float v = Sb[(size_t)(ty*128 + ii)*NLQ + j];
    const float nm = fmaxf(m, v);
    s = s * __expf(m - nm) + __expf(v - nm);
    m = nm;
  }
  redm[ty][tx] = m; reds[ty][tx] = s;
  __syncthreads();
  if (ty == 0) {
    #pragma unroll
    for (int y = 1; y < 8; ++y) {
      const float m2 = redm[y][tx], s2 = reds[y][tx];
      const float nm = fmaxf(m, m2);
      s = s * __expf(m - nm) + s2 * __expf(m2 - nm);
      m = nm;
    }
    ws[OFF_CMAX + (size_t)b*NLQ + j] = m;
    ws[OFF_CSUM + (size_t)b*NLQ + j] = 1.0f / s;
  }
}

// ===== M (MFMA): M[d,j] = sum_k C[d,k]*S__[k,j], split-K=2, d-tile 64 ======
// A = C rows (k-contiguous, bf16 LDS [64][40] pad -> 2-way/free b128 reads);
// B = S__ columns (fp32 padded LDS + cvt_pk). bf16 partial M output.
__global__ __launch_bounds__(256) void k_m(const float* __restrict__ C,
                                           float* __restrict__ ws) {
  __shared__ float  Ps[32][129];    // [k][j] exp'd col-softmax probs, padded
  __shared__ ushort Cs16[64][40];   // [d][k] bf16 rows, pad 40
  __shared__ float cmS[128], icS[128];
  const int n   = blockIdx.x;
  const int rr  = n & 7, qq = n >> 3;
  const int dq  = qq & 3;               // member: d quarter
  const int g   = (qq >> 2) * 8 + rr;   // group = (ksp, b)
  const int b   = g & 63;
  const int ksp = g >> 6;
  const int t   = threadIdx.x;
  const int l   = t & 63, w = t >> 6;
  const int lm  = l & 15, lg = l >> 4;
  if (t < 128) {
    cmS[t] = ws[OFF_CMAX + (size_t)b*NLQ + t];
    icS[t] = ws[OFF_CSUM + (size_t)b*NLQ + t];
  }
  f32x4 acc[8];
  #pragma unroll
  for (int nf = 0; nf < 8; ++nf) acc[nf] = (f32x4)0.0f;

  const float* Cb = C + (size_t)b*ND*NLC + (size_t)dq*64*NLC;
  const float* Sb = ws + OFF_S + (size_t)b*NLC*NLQ;
  const int kbase = ksp * 512;

  for (int kt = 0; kt < 16; ++kt) {
    const int k0 = kbase + kt*32;
    __syncthreads();
    #pragma unroll
    for (int p = 0; p < 4; ++p) {        // stage P = exp(S - cmax)*icsum
      const int f = p*256 + t;
      const int kk = f >> 5, j4 = f & 31;
      const float4 sv = *(const float4*)&Sb[(size_t)(k0+kk)*NLQ + j4*4];
      const int j = j4*4;
      float4 pv;
      pv.x = __expf(sv.x - cmS[j+0]) * icS[j+0];
      pv.y = __expf(sv.y - cmS[j+1]) * icS[j+1];
      pv.z = __expf(sv.z - cmS[j+2]) * icS[j+2];
      pv.w = __expf(sv.w - cmS[j+3]) * icS[j+3];
      *(float4*)&Ps[kk][j4*4] = pv;
    }
    #pragma unroll
    for (int p = 0; p < 2; ++p) {        // stage C rows as bf16
      const int f = p*256 + t;
      const int dl = f >> 3, kq = f & 7;
      const float4 cv = *(const float4*)&Cb[(size_t)dl*NLC + k0 + kq*4];
      uint2 pk;
      pk.x = cvtpk(cv.x, cv.y);
      pk.y = cvtpk(cv.z, cv.w);
      *(uint2*)&Cs16[dl][kq*4] = pk;
    }
    __syncthreads();
    // A-frag: C rows, k-contiguous b128
    union { uint32_t u[4]; bf16x8 v; } ca;
    *(uint4*)ca.u = *(const uint4*)&Cs16[w*16 + lm][lg*8];
    // B-frags: P columns + cvt_pk
    #pragma unroll
    for (int nf = 0; nf < 8; ++nf) {
      const int j = nf*16 + lm;
      union { uint32_t u[4]; bf16x8 v; } cb;
      #pragma unroll
      for (int kk = 0; kk < 4; ++kk)
        cb.u[kk] = cvtpk(Ps[lg*8 + kk*2][j], Ps[lg*8 + kk*2 + 1][j]);
      acc[nf] = __builtin_amdgcn_mfma_f32_16x16x32_bf16(ca.v, cb.v, acc[nf], 0, 0, 0);
    }
  }
  // D: row = d = w*16 + lg*4 + r, col = j = nf*16 + lm
  ushort* Mp = (ushort*)(ws + OFF_M)
             + ((size_t)ksp*NB + b)*ND*NLQ + (size_t)dq*64*NLQ;
  #pragma unroll
  for (int nf = 0; nf < 8; ++nf) {
    #pragma unroll
    for (int r = 0; r < 4; ++r) {
      const int d = w*16 + lg*4 + r;
      Mp[(size_t)d*NLQ + nf*16 + lm] = (ushort)f2bf(acc[nf][r]);
    }
  }
}

// ==== final (MFMA): A = Q*S_^T, Bm = M*S_^T, out = [C, A, C*A, C*Bm] ========
// Unchanged structure; threefry compare -> exact integer form.
__global__ __launch_bounds__(256, 3) void k_final(const float* __restrict__ C,
                                                  const float* __restrict__ Q,
                                                  float* __restrict__ ws,
                                                  float* __restrict__ out) {
  __shared__ __align__(16) uint8_t smem[49152];
  ushort (*St)[128] = (ushort(*)[128])smem;            // [i 128][j 128] 32KB
  ushort (*Qt)[128] = (ushort(*)[128])(smem + 32768);  // [d 32][j 128]  8KB
  ushort (*Mt)[128] = (ushort(*)[128])(smem + 40960);  // [d 32][j 128]  8KB
  float  (*At)[128] = (float (*)[128])smem;            // epilogue [d 32][i 128]
  float  (*Bt)[128] = (float (*)[128])(smem + 16384);

  const int n  = blockIdx.x;
  const int r8 = n & 7, q = n >> 3;
  const int m  = q & 7;                 // member: d0 block
  const int g  = (q >> 3) * 8 + r8;     // group = (i0, b), one XCD
  const int b  = g & 63;
  const int i0 = (g >> 6) * 128;
  const int d0 = m * 32;
  const int t  = threadIdx.x;

  const float* Sb  = ws + OFF_S + ((size_t)b*NLC + (size_t)i0)*NLQ;
  const float* rmp = ws + OFF_RMAX + (size_t)b*NLC + i0;
  const float* irp = ws + OFF_RSUM + (size_t)b*NLC + i0;
  #pragma unroll
  for (int p = 0; p < 16; ++p) {
    const int f  = p*256 + t;
    const int j4 = f & 31;
    const int il = f >> 5;
    const float4 sv = *(const float4*)&Sb[(size_t)il*NLQ + j4*4];
    const float rm = rmp[il], ir = irp[il];
    uint2 pk;
    pk.x = f2bf(__expf(sv.x - rm) * ir) | (f2bf(__expf(sv.y - rm) * ir) << 16);
    pk.y = f2bf(__expf(sv.z - rm) * ir) | (f2bf(__expf(sv.w - rm) * ir) << 16);
    *(uint2*)&St[il][(j4*4) ^ ((il & 7) << 3)] = pk;
  }
  const float*  Qb  = Q + (size_t)b*ND*NLQ + (size_t)d0*NLQ;
  const ushort* M0p = (const ushort*)(ws + OFF_M)
                    + (size_t)b*ND*NLQ + (size_t)d0*NLQ;
  const ushort* M1p = M0p + (size_t)NB*ND*NLQ;
  #pragma unroll
  for (int p = 0; p < 4; ++p) {
    const int f  = p*256 + t;
    const int j4 = f & 31;
    const int dl = f >> 5;
    const int col = (j4*4) ^ ((dl & 7) << 3);
    const float4 qv = *(const float4*)&Qb[(size_t)dl*NLQ + j4*4];
    uint2 pq;
    pq.x = f2bf(qv.x) | (f2bf(qv.y) << 16);
    pq.y = f2bf(qv.z) | (f2bf(qv.w) << 16);
    *(uint2*)&Qt[dl][col] = pq;
    const uint2 u0 = *(const uint2*)&M0p[(size_t)dl*NLQ + j4*4];
    const uint2 u1 = *(const uint2*)&M1p[(size_t)dl*NLQ + j4*4];
    uint2 pm;
    pm.x = f2bf(bflo(u0.x) + bflo(u1.x)) | (f2bf(bfhi(u0.x) + bfhi(u1.x)) << 16);
    pm.y = f2bf(bflo(u0.y) + bflo(u1.y)) | (f2bf(bfhi(u0.y) + bfhi(u1.y)) << 16);
    *(uint2*)&Mt[dl][col] = pm;
  }
  __syncthreads();

  const int w  = t >> 6;
  const int wd = w & 1, wi = w >> 1;
  const int l  = t & 63;
  const int lm = l & 15;
  const int lk = (l >> 4) * 8;
  const int sw = (lm & 7) << 3;

  f32x4 accA[4], accB[4];
  #pragma unroll
  for (int f = 0; f < 4; ++f) { accA[f] = (f32x4)0.0f; accB[f] = (f32x4)0.0f; }

  #pragma unroll
  for (int ks = 0; ks < 4; ++ks) {
    const int koff = (ks*32 + lk) ^ sw;
    const bf16x8 qf = *(const bf16x8*)&Qt[wd*16 + lm][koff];
    const bf16x8 mf = *(const bf16x8*)&Mt[wd*16 + lm][koff];
    #pragma unroll
    for (int f = 0; f < 4; ++f) {
      const bf16x8 sf = *(const bf16x8*)&St[(wi*4 + f)*16 + lm][koff];
      accA[f] = __builtin_amdgcn_mfma_f32_16x16x32_bf16(qf, sf, accA[f], 0, 0, 0);
      accB[f] = __builtin_amdgcn_mfma_f32_16x16x32_bf16(mf, sf, accB[f], 0, 0, 0);
    }
  }
  __syncthreads();

  const int dwl = wd*16 + (l >> 4)*4;
  #pragma unroll
  for (int f = 0; f < 4; ++f) {
    const int i = (wi*4 + f)*16 + lm;
    #pragma unroll
    for (int r = 0; r < 4; ++r) {
      const int dl = dwl + r;
      const int isw = i ^ ((dl & 7) << 2);
      At[dl][isw] = accA[f][r];
      Bt[dl][isw] = accB[f][r];
    }
  }
  __syncthreads();

  const int il4 = (t & 31) * 4;
  const int dg8 = t >> 5;
  const float* Cb = C + (size_t)b*ND*NLC;
  #pragma unroll 1
  for (int dd = 0; dd < 4; ++dd) {
    const int dl = dd*8 + dg8;
    const int d  = d0 + dl;
    const int isw = il4 ^ ((dl & 7) << 2);
    const float4 a4 = *(const float4*)&At[dl][isw];
    const float4 b4 = *(const float4*)&Bt[dl][isw];
    const float4 c4 = *(const float4*)&Cb[(size_t)d*NLC + i0 + il4];
    const float av[4] = {a4.x, a4.y, a4.z, a4.w};
    const float bv[4] = {b4.x, b4.y, b4.z, b4.w};
    const float cv[4] = {c4.x, c4.y, c4.z, c4.w};
    #pragma unroll
    for (int s = 0; s < 4; ++s) {
      const uint32_t nb = ((((uint32_t)b << 10) + (uint32_t)(s*ND + d)) << 10)
                          + (uint32_t)(i0 + il4);
      float ov[4];
      #pragma unroll
      for (int e = 0; e < 4; ++e) {
        const uint32_t bits = threefry_xor(0u, nb + (uint32_t)e);
        float v;
        if (s == 0)      v = cv[e];
        else if (s == 1) v = av[e];
        else if (s == 2) v = cv[e] * av[e];
        else             v = cv[e] * bv[e];
        // u < 0.9f  <=>  (bits>>9) < 7549747  (0.9f = 7549747/2^23 exactly)
        ov[e] = ((bits >> 9) < 7549747u) ? v * INVKEEP : 0.0f;
      }
      *(float4*)&out[nb] = make_float4(ov[0], ov[1], ov[2], ov[3]);
    }
  }
}

extern "C" void kernel_launch(void* const* d_in, const int* in_sizes, int n_in,
                              void* d_out, int out_size, void* d_ws, size_t ws_size,
                              hipStream_t stream) {
  (void)in_sizes; (void)n_in; (void)out_size; (void)ws_size;
  const float* C = (const float*)d_in[0];
  const float* Q = (const float*)d_in[1];
  const float* W = (const float*)d_in[2];
  float* out = (float*)d_out;
  float* ws  = (float*)d_ws;

  hipLaunchKernelGGL(k_sq,       dim3(NB),    dim3(128), 0, stream, Q, W, ws);
  hipLaunchKernelGGL(k_s,        dim3(512),   dim3(256), 0, stream, C, Q, W, ws);
  hipLaunchKernelGGL(k_colstats, dim3(4, NB), dim3(256), 0, stream, ws);
  hipLaunchKernelGGL(k_m,        dim3(512),   dim3(256), 0, stream, C, ws);
  hipLaunchKernelGGL(k_final,    dim3(4096),  dim3(256), 0, stream, C, Q, ws, out);
}

// Round 9
// 244.462 us; speedup vs baseline: 1.8514x; 1.0236x over previous
//
#include <hip/hip_runtime.h>
#include <stdint.h>
#include <stddef.h>

#define NB  64
#define ND  256
#define NLC 1024
#define NLQ 128
#define INVKEEP (1.0f/0.9f)

// ---- workspace layout (float offsets); total 14,835,712 floats = 56.6 MiB ----
#define OFF_SQ    0u            // NB*NLQ
#define OFF_RMAX  8192u         // NB*NLC  (row max of S)
#define OFF_RSUM  73728u        // NB*NLC  (RECIPROCAL row sum)
#define OFF_CMAX  139264u       // NB*NLQ  (col max)
#define OFF_CSUM  147456u       // NB*NLQ  (RECIPROCAL col sum)
#define OFF_S     155648u       // NB*NLC*NLQ fp32 raw S
#define OFF_SBF   8544256u      // NB*NLC*NLQ bf16 S_ (row-softmaxed)
#define OFF_M     12738560u     // NB*ND*NLQ  bf16 M (final, no partials)
#define OFF_QB    13787136u     // NB*ND*NLQ  bf16 Q

typedef float f32x4  __attribute__((ext_vector_type(4)));
typedef short bf16x8 __attribute__((ext_vector_type(8)));

// bf16 helpers
__device__ __forceinline__ uint32_t f2bf(float x) {
  const uint32_t u = __float_as_uint(x);
  return (u + 0x7fffu + ((u >> 16) & 1u)) >> 16;
}
// packed f32x2 -> bf16x2 (lo = first arg), HW RNE
__device__ __forceinline__ uint32_t cvtpk(float lo, float hi) {
  uint32_t r;
  asm("v_cvt_pk_bf16_f32 %0, %1, %2" : "=v"(r) : "v"(lo), "v"(hi));
  return r;
}

// ================= threefry2x32, key=(0,42); bits = o0^o1 (verified r2) =====
__device__ __forceinline__ void tf_round(uint32_t& a, uint32_t& b, const int r) {
  a += b;
  b = (b << r) | (b >> (32 - r));
  b ^= a;
}
__device__ __forceinline__ uint32_t threefry_xor(uint32_t x0, uint32_t x1) {
  const uint32_t ks0 = 0u, ks1 = 42u, ks2 = 0x1BD11BDAu ^ 0u ^ 42u;
  x0 += ks0; x1 += ks1;
  tf_round(x0,x1,13); tf_round(x0,x1,15); tf_round(x0,x1,26); tf_round(x0,x1,6);
  x0 += ks1; x1 += ks2 + 1u;
  tf_round(x0,x1,17); tf_round(x0,x1,29); tf_round(x0,x1,16); tf_round(x0,x1,24);
  x0 += ks2; x1 += ks0 + 2u;
  tf_round(x0,x1,13); tf_round(x0,x1,15); tf_round(x0,x1,26); tf_round(x0,x1,6);
  x0 += ks0; x1 += ks1 + 3u;
  tf_round(x0,x1,17); tf_round(x0,x1,29); tf_round(x0,x1,16); tf_round(x0,x1,24);
  x0 += ks1; x1 += ks2 + 4u;
  tf_round(x0,x1,13); tf_round(x0,x1,15); tf_round(x0,x1,26); tf_round(x0,x1,6);
  x0 += ks2; x1 += ks0 + 5u;
  return x0 ^ x1;
}

// ================= sq[b,j] = sum_d wq[d] * Q[b,d,j] ==========================
__global__ __launch_bounds__(128) void k_sq(const float* __restrict__ Q,
                                            const float* __restrict__ W,
                                            float* __restrict__ ws) {
  const int b = blockIdx.x;
  const int j = threadIdx.x;
  const float* wq = W + (size_t)b*768;
  const float* Qb = Q + (size_t)b*ND*NLQ;
  float acc = 0.0f;
  for (int d = 0; d < ND; ++d) acc = fmaf(wq[d], Qb[(size_t)d*NLQ + j], acc);
  ws[OFF_SQ + (size_t)b*NLQ + j] = acc;
}

// ================= Q -> bf16, materialized once ==============================
__global__ __launch_bounds__(256) void k_qb(const float* __restrict__ Q,
                                            float* __restrict__ ws) {
  const size_t idx = ((size_t)blockIdx.x * 256 + threadIdx.x) * 8;
  ushort* qb = (ushort*)(ws + OFF_QB);
  const float4 a = *(const float4*)&Q[idx];
  const float4 c = *(const float4*)&Q[idx + 4];
  uint4 pk;
  pk.x = cvtpk(a.x, a.y); pk.y = cvtpk(a.z, a.w);
  pk.z = cvtpk(c.x, c.y); pk.w = cvtpk(c.z, c.w);
  *(uint4*)&qb[idx] = pk;
}

// ===== S (MFMA): S[i,j] = sum_d C[d,i]*Q'[d,j] + sq[j], fused row stats =====
// Writes raw S fp32 (for colstats/k_m) AND row-softmaxed S_ bf16 (for k_final).
__global__ __launch_bounds__(256) void k_s(const float* __restrict__ C,
                                           const float* __restrict__ Q,
                                           const float* __restrict__ W,
                                           float* __restrict__ ws) {
  __shared__ float Cs[32][129];     // [d][i] fp32, padded
  __shared__ float Qs[32][129];     // [d][j] fp32 (Q'=wm*Q+wc), padded
  __shared__ float wmS[256], wcS[256], sqS[128];
  const int n  = blockIdx.x;
  const int rr = n & 7, qq = n >> 3;
  const int it = qq & 7;                 // member: i-tile
  const int b  = (qq >> 3) * 8 + rr;     // group: batch
  const int i0 = it * 128;
  const int t  = threadIdx.x;
  wcS[t] = W[(size_t)b*768 + 256 + t];
  wmS[t] = W[(size_t)b*768 + 512 + t];
  if (t < 128) sqS[t] = ws[OFF_SQ + (size_t)b*NLQ + t];

  const float* Cb = C + (size_t)b*ND*NLC;
  const float* Qb = Q + (size_t)b*ND*NLQ;
  const int l  = t & 63, w = t >> 6;
  const int lm = l & 15, lg = l >> 4;

  f32x4 acc[2][8];
  #pragma unroll
  for (int mg = 0; mg < 2; ++mg)
    #pragma unroll
    for (int nf = 0; nf < 8; ++nf) acc[mg][nf] = (f32x4)0.0f;

  for (int d0 = 0; d0 < ND; d0 += 32) {
    __syncthreads();
    #pragma unroll
    for (int p = 0; p < 4; ++p) {        // stage C and Q' tiles (coalesced)
      const int f  = p*256 + t;
      const int dk = f >> 5, x4 = f & 31;
      *(float4*)&Cs[dk][x4*4] = *(const float4*)&Cb[(size_t)(d0+dk)*NLC + i0 + x4*4];
      const float4 qv = *(const float4*)&Qb[(size_t)(d0+dk)*NLQ + x4*4];
      const float wmv = wmS[d0+dk], wcv = wcS[d0+dk];
      float4 o;
      o.x = fmaf(wmv, qv.x, wcv);
      o.y = fmaf(wmv, qv.y, wcv);
      o.z = fmaf(wmv, qv.z, wcv);
      o.w = fmaf(wmv, qv.w, wcv);
      *(float4*)&Qs[dk][x4*4] = o;
    }
    __syncthreads();
    bf16x8 bq[8];
    #pragma unroll
    for (int nf = 0; nf < 8; ++nf) {
      const int j = nf*16 + lm;
      union { uint32_t u[4]; bf16x8 v; } cc;
      #pragma unroll
      for (int kk = 0; kk < 4; ++kk)
        cc.u[kk] = cvtpk(Qs[lg*8 + kk*2][j], Qs[lg*8 + kk*2 + 1][j]);
      bq[nf] = cc.v;
    }
    #pragma unroll
    for (int mg = 0; mg < 2; ++mg) {
      const int i = w*32 + mg*16 + lm;
      union { uint32_t u[4]; bf16x8 v; } ca;
      #pragma unroll
      for (int kk = 0; kk < 4; ++kk)
        ca.u[kk] = cvtpk(Cs[lg*8 + kk*2][i], Cs[lg*8 + kk*2 + 1][i]);
      #pragma unroll
      for (int nf = 0; nf < 8; ++nf)
        acc[mg][nf] = __builtin_amdgcn_mfma_f32_16x16x32_bf16(ca.v, bq[nf], acc[mg][nf], 0, 0, 0);
    }
  }

  // epilogue: +sq, row stats, store raw S fp32 + normalized S_ bf16
  float sqv[8];
  #pragma unroll
  for (int nf = 0; nf < 8; ++nf) sqv[nf] = sqS[nf*16 + lm];
  float*  Sb   = ws + OFF_S + ((size_t)b*NLC + (size_t)i0)*NLQ;
  ushort* Sb16 = (ushort*)(ws + OFF_SBF) + ((size_t)b*NLC + (size_t)i0)*NLQ;
  #pragma unroll
  for (int mg = 0; mg < 2; ++mg) {
    #pragma unroll
    for (int r = 0; r < 4; ++r) {
      const int row = w*32 + mg*16 + lg*4 + r;   // i within tile
      float sv[8];
      #pragma unroll
      for (int nf = 0; nf < 8; ++nf) sv[nf] = acc[mg][nf][r] + sqv[nf];
      float mx = sv[0];
      #pragma unroll
      for (int nf = 1; nf < 8; ++nf) mx = fmaxf(mx, sv[nf]);
      mx = fmaxf(mx, __shfl_xor(mx, 1));
      mx = fmaxf(mx, __shfl_xor(mx, 2));
      mx = fmaxf(mx, __shfl_xor(mx, 4));
      mx = fmaxf(mx, __shfl_xor(mx, 8));
      float sm = 0.0f;
      #pragma unroll
      for (int nf = 0; nf < 8; ++nf) sm += __expf(sv[nf] - mx);
      sm += __shfl_xor(sm, 1);
      sm += __shfl_xor(sm, 2);
      sm += __shfl_xor(sm, 4);
      sm += __shfl_xor(sm, 8);
      const float ir = 1.0f / sm;
      #pragma unroll
      for (int nf = 0; nf < 8; ++nf) {
        Sb[(size_t)row*NLQ + nf*16 + lm] = sv[nf];
        Sb16[(size_t)row*NLQ + nf*16 + lm] = (ushort)f2bf(__expf(sv[nf] - mx) * ir);
      }
      if (lm == 0) {
        ws[OFF_RMAX + (size_t)b*NLC + i0 + row] = mx;
        ws[OFF_RSUM + (size_t)b*NLC + i0 + row] = ir;
      }
    }
  }
}

// ==== column softmax stats over i (axis=1): SINGLE-PASS online (m, s) ======
__global__ __launch_bounds__(256) void k_colstats(float* __restrict__ ws) {
  __shared__ float redm[8][32], reds[8][32];
  const int b  = blockIdx.y;
  const int jq = blockIdx.x;
  const int tx = threadIdx.x & 31;
  const int ty = threadIdx.x >> 5;
  const int j  = jq*32 + tx;
  const float* Sb = ws + OFF_S + (size_t)b*NLC*NLQ;
  float m = -3.0e38f, s = 0.0f;
  for (int ii = 0; ii < 128; ++ii) {
    const float v = Sb[(size_t)(ty*128 + ii)*NLQ + j];
    const float nm = fmaxf(m, v);
    s = s * __expf(m - nm) + __expf(v - nm);
    m = nm;
  }
  redm[ty][tx] = m; reds[ty][tx] = s;
  __syncthreads();
  if (ty == 0) {
    #pragma unroll
    for (int y = 1; y < 8; ++y) {
      const float m2 = redm[y][tx], s2 = reds[y][tx];
      const float nm = fmaxf(m, m2);
      s = s * __expf(m - nm) + s2 * __expf(m2 - nm);
      m = nm;
    }
    ws[OFF_CMAX + (size_t)b*NLQ + j] = m;
    ws[OFF_CSUM + (size_t)b*NLQ + j] = 1.0f / s;
  }
}

// ===== M (MFMA): M[d,j] = sum_k C[d,k]*S__[k,j], FULL K=1024, d-tile 32 =====
// Grid 512 (8 dq x 64 b, XCD-grouped) = 2 blocks/CU. Writes final M bf16.
__global__ __launch_bounds__(256) void k_m(const float* __restrict__ C,
                                           float* __restrict__ ws) {
  __shared__ float  Ps[32][129];    // [k][j] exp'd col-softmax probs, padded
  __shared__ ushort Cs16[32][40];   // [d][k] bf16 rows, pad 40
  __shared__ float cmS[128], icS[128];
  const int n  = blockIdx.x;
  const int rr = n & 7, qq = n >> 3;
  const int dq = qq & 7;                // member: d-tile (32 rows)
  const int b  = (qq >> 3) * 8 + rr;    // group: batch
  const int t  = threadIdx.x;
  const int l  = t & 63, w = t >> 6;
  const int wd = w & 1, wj = w >> 1;    // d-strip 16, j-half 64
  const int lm = l & 15, lg = l >> 4;
  if (t < 128) {
    cmS[t] = ws[OFF_CMAX + (size_t)b*NLQ + t];
    icS[t] = ws[OFF_CSUM + (size_t)b*NLQ + t];
  }
  f32x4 acc[4];
  #pragma unroll
  for (int nf = 0; nf < 4; ++nf) acc[nf] = (f32x4)0.0f;

  const float* Cb = C + (size_t)b*ND*NLC + (size_t)dq*32*NLC;
  const float* Sb = ws + OFF_S + (size_t)b*NLC*NLQ;

  for (int kt = 0; kt < 32; ++kt) {
    const int k0 = kt*32;
    __syncthreads();
    #pragma unroll
    for (int p = 0; p < 4; ++p) {        // stage P = exp(S - cmax)*icsum
      const int f = p*256 + t;
      const int kk = f >> 5, j4 = f & 31;
      const float4 sv = *(const float4*)&Sb[(size_t)(k0+kk)*NLQ + j4*4];
      const int j = j4*4;
      float4 pv;
      pv.x = __expf(sv.x - cmS[j+0]) * icS[j+0];
      pv.y = __expf(sv.y - cmS[j+1]) * icS[j+1];
      pv.z = __expf(sv.z - cmS[j+2]) * icS[j+2];
      pv.w = __expf(sv.w - cmS[j+3]) * icS[j+3];
      *(float4*)&Ps[kk][j4*4] = pv;
    }
    {                                    // stage C rows as bf16 (32 d x 32 k)
      const int dl = t >> 3, kq = t & 7;
      const float4 cv = *(const float4*)&Cb[(size_t)dl*NLC + k0 + kq*4];
      uint2 pk;
      pk.x = cvtpk(cv.x, cv.y);
      pk.y = cvtpk(cv.z, cv.w);
      *(uint2*)&Cs16[dl][kq*4] = pk;
    }
    __syncthreads();
    union { uint32_t u[4]; bf16x8 v; } ca;
    *(uint4*)ca.u = *(const uint4*)&Cs16[wd*16 + lm][lg*8];
    #pragma unroll
    for (int nf = 0; nf < 4; ++nf) {
      const int j = wj*64 + nf*16 + lm;
      union { uint32_t u[4]; bf16x8 v; } cb;
      #pragma unroll
      for (int kk = 0; kk < 4; ++kk)
        cb.u[kk] = cvtpk(Ps[lg*8 + kk*2][j], Ps[lg*8 + kk*2 + 1][j]);
      acc[nf] = __builtin_amdgcn_mfma_f32_16x16x32_bf16(ca.v, cb.v, acc[nf], 0, 0, 0);
    }
  }
  // D: row = d = wd*16 + lg*4 + r, col = j = wj*64 + nf*16 + lm
  ushort* Mp = (ushort*)(ws + OFF_M) + (size_t)b*ND*NLQ + (size_t)dq*32*NLQ;
  #pragma unroll
  for (int nf = 0; nf < 4; ++nf) {
    #pragma unroll
    for (int r = 0; r < 4; ++r) {
      const int d = wd*16 + lg*4 + r;
      Mp[(size_t)d*NLQ + wj*64 + nf*16 + lm] = (ushort)f2bf(acc[nf][r]);
    }
  }
}

// ==== final (MFMA): A = Q*S_^T, Bm = M*S_^T, out = [C, A, C*A, C*Bm] ========
// Staging is now PURE swizzled copies of precomputed bf16 (no exp/pack VALU).
__global__ __launch_bounds__(256, 3) void k_final(const float* __restrict__ C,
                                                  float* __restrict__ ws,
                                                  float* __restrict__ out) {
  __shared__ __align__(16) uint8_t smem[49152];
  ushort (*St)[128] = (ushort(*)[128])smem;            // [i 128][j 128] 32KB
  ushort (*Qt)[128] = (ushort(*)[128])(smem + 32768);  // [d 32][j 128]  8KB
  ushort (*Mt)[128] = (ushort(*)[128])(smem + 40960);  // [d 32][j 128]  8KB
  float  (*At)[128] = (float (*)[128])smem;            // epilogue [d 32][i 128]
  float  (*Bt)[128] = (float (*)[128])(smem + 16384);

  const int n  = blockIdx.x;
  const int r8 = n & 7, q = n >> 3;
  const int m  = q & 7;                 // member: d0 block
  const int g  = (q >> 3) * 8 + r8;     // group = (i0, b), one XCD
  const int b  = g & 63;
  const int i0 = (g >> 6) * 128;
  const int d0 = m * 32;
  const int t  = threadIdx.x;

  const ushort* Sp = (const ushort*)(ws + OFF_SBF) + ((size_t)b*NLC + i0)*NLQ;
  #pragma unroll
  for (int p = 0; p < 16; ++p) {        // S_ bf16: pure swizzled copy
    const int f  = p*256 + t;
    const int j4 = f & 31;
    const int il = f >> 5;
    *(uint2*)&St[il][(j4*4) ^ ((il & 7) << 3)] =
        *(const uint2*)&Sp[(size_t)il*NLQ + j4*4];
  }
  const ushort* Qp = (const ushort*)(ws + OFF_QB) + (size_t)b*ND*NLQ + (size_t)d0*NLQ;
  const ushort* Mp = (const ushort*)(ws + OFF_M)  + (size_t)b*ND*NLQ + (size_t)d0*NLQ;
  #pragma unroll
  for (int p = 0; p < 4; ++p) {         // Q/M bf16: pure swizzled copies
    const int f  = p*256 + t;
    const int j4 = f & 31;
    const int dl = f >> 5;
    const int col = (j4*4) ^ ((dl & 7) << 3);
    *(uint2*)&Qt[dl][col] = *(const uint2*)&Qp[(size_t)dl*NLQ + j4*4];
    *(uint2*)&Mt[dl][col] = *(const uint2*)&Mp[(size_t)dl*NLQ + j4*4];
  }
  __syncthreads();

  const int w  = t >> 6;
  const int wd = w & 1, wi = w >> 1;
  const int l  = t & 63;
  const int lm = l & 15;
  const int lk = (l >> 4) * 8;
  const int sw = (lm & 7) << 3;

  f32x4 accA[4], accB[4];
  #pragma unroll
  for (int f = 0; f < 4; ++f) { accA[f] = (f32x4)0.0f; accB[f] = (f32x4)0.0f; }

  #pragma unroll
  for (int ks = 0; ks < 4; ++ks) {
    const int koff = (ks*32 + lk) ^ sw;
    const bf16x8 qf = *(const bf16x8*)&Qt[wd*16 + lm][koff];
    const bf16x8 mf = *(const bf16x8*)&Mt[wd*16 + lm][koff];
    #pragma unroll
    for (int f = 0; f < 4; ++f) {
      const bf16x8 sf = *(const bf16x8*)&St[(wi*4 + f)*16 + lm][koff];
      accA[f] = __builtin_amdgcn_mfma_f32_16x16x32_bf16(qf, sf, accA[f], 0, 0, 0);
      accB[f] = __builtin_amdgcn_mfma_f32_16x16x32_bf16(mf, sf, accB[f], 0, 0, 0);
    }
  }
  __syncthreads();   // staging buffers dead; reuse as At/Bt

  const int dwl = wd*16 + (l >> 4)*4;
  #pragma unroll
  for (int f = 0; f < 4; ++f) {
    const int i = (wi*4 + f)*16 + lm;
    #pragma unroll
    for (int r = 0; r < 4; ++r) {
      const int dl = dwl + r;
      const int isw = i ^ ((dl & 7) << 2);
      At[dl][isw] = accA[f][r];
      Bt[dl][isw] = accB[f][r];
    }
  }
  __syncthreads();

  const int il4 = (t & 31) * 4;
  const int dg8 = t >> 5;
  const float* Cb = C + (size_t)b*ND*NLC;
  #pragma unroll 1                      // keep body small: fits L1I
  for (int dd = 0; dd < 4; ++dd) {
    const int dl = dd*8 + dg8;
    const int d  = d0 + dl;
    const int isw = il4 ^ ((dl & 7) << 2);
    const float4 a4 = *(const float4*)&At[dl][isw];
    const float4 b4 = *(const float4*)&Bt[dl][isw];
    const float4 c4 = *(const float4*)&Cb[(size_t)d*NLC + i0 + il4];
    const float av[4] = {a4.x, a4.y, a4.z, a4.w};
    const float bv[4] = {b4.x, b4.y, b4.z, b4.w};
    const float cv[4] = {c4.x, c4.y, c4.z, c4.w};
    #pragma unroll
    for (int s = 0; s < 4; ++s) {
      const uint32_t nb = ((((uint32_t)b << 10) + (uint32_t)(s*ND + d)) << 10)
                          + (uint32_t)(i0 + il4);
      float ov[4];
      #pragma unroll
      for (int e = 0; e < 4; ++e) {
        const uint32_t bits = threefry_xor(0u, nb + (uint32_t)e);
        float v;
        if (s == 0)      v = cv[e];
        else if (s == 1) v = av[e];
        else if (s == 2) v = cv[e] * av[e];
        else             v = cv[e] * bv[e];
        // u < 0.9f  <=>  (bits>>9) < 7549747  (0.9f = 7549747/2^23 exactly)
        ov[e] = ((bits >> 9) < 7549747u) ? v * INVKEEP : 0.0f;
      }
      *(float4*)&out[nb] = make_float4(ov[0], ov[1], ov[2], ov[3]);
    }
  }
}

extern "C" void kernel_launch(void* const* d_in, const int* in_sizes, int n_in,
                              void* d_out, int out_size, void* d_ws, size_t ws_size,
                              hipStream_t stream) {
  (void)in_sizes; (void)n_in; (void)out_size; (void)ws_size;
  const float* C = (const float*)d_in[0];
  const float* Q = (const float*)d_in[1];
  const float* W = (const float*)d_in[2];
  float* out = (float*)d_out;
  float* ws  = (float*)d_ws;

  hipLaunchKernelGGL(k_sq,       dim3(NB),    dim3(128), 0, stream, Q, W, ws);
  hipLaunchKernelGGL(k_qb,       dim3(1024),  dim3(256), 0, stream, Q, ws);
  hipLaunchKernelGGL(k_s,        dim3(512),   dim3(256), 0, stream, C, Q, W, ws);
  hipLaunchKernelGGL(k_colstats, dim3(4, NB), dim3(256), 0, stream, ws);
  hipLaunchKernelGGL(k_m,        dim3(512),   dim3(256), 0, stream, C, ws);
  hipLaunchKernelGGL(k_final,    dim3(4096),  dim3(256), 0, stream, C, ws, out);
}

// Round 11
// 217.426 us; speedup vs baseline: 2.0816x; 1.1243x over previous
//
#include <hip/hip_runtime.h>
#include <stdint.h>
#include <stddef.h>

#define NB  64
#define ND  256
#define NLC 1024
#define NLQ 128
#define INVKEEP (1.0f/0.9f)

// ---- workspace layout (float offsets); total 14,835,712 floats = 56.6 MiB ----
#define OFF_SQ    0u            // NB*NLQ
#define OFF_U     8192u         // NB*NLC  u(i) = exp(rmax_i)*rowsum_i
#define OFF_V     139264u       // NB*NLQ  v(j) = exp(-cmax_j)/colsum_j
#define OFF_COLP  155648u       // NB*8*NLQ*2 col partials (m,s)
#define OFF_SBT   286720u       // NB*NLQ*NLC bf16 S_^T (row-softmaxed, transposed)
#define OFF_SBF   8544256u      // NB*NLC*NLQ bf16 S_ (row-softmaxed)
#define OFF_M     12738560u     // NB*ND*NLQ  bf16 M (final)
#define OFF_QB    13787136u     // NB*ND*NLQ  bf16 Q

typedef float f32x4  __attribute__((ext_vector_type(4)));
typedef short bf16x8 __attribute__((ext_vector_type(8)));

__device__ __forceinline__ uint32_t f2bf(float x) {
  const uint32_t u = __float_as_uint(x);
  return (u + 0x7fffu + ((u >> 16) & 1u)) >> 16;
}
__device__ __forceinline__ uint32_t cvtpk(float lo, float hi) {
  uint32_t r;
  asm("v_cvt_pk_bf16_f32 %0, %1, %2" : "=v"(r) : "v"(lo), "v"(hi));
  return r;
}

// ================= threefry2x32, key=(0,42); bits = o0^o1 (verified r2) =====
__device__ __forceinline__ void tf_round(uint32_t& a, uint32_t& b, const int r) {
  a += b;
  b = (b << r) | (b >> (32 - r));
  b ^= a;
}
__device__ __forceinline__ uint32_t threefry_xor(uint32_t x0, uint32_t x1) {
  const uint32_t ks0 = 0u, ks1 = 42u, ks2 = 0x1BD11BDAu ^ 0u ^ 42u;
  x0 += ks0; x1 += ks1;
  tf_round(x0,x1,13); tf_round(x0,x1,15); tf_round(x0,x1,26); tf_round(x0,x1,6);
  x0 += ks1; x1 += ks2 + 1u;
  tf_round(x0,x1,17); tf_round(x0,x1,29); tf_round(x0,x1,16); tf_round(x0,x1,24);
  x0 += ks2; x1 += ks0 + 2u;
  tf_round(x0,x1,13); tf_round(x0,x1,15); tf_round(x0,x1,26); tf_round(x0,x1,6);
  x0 += ks0; x1 += ks1 + 3u;
  tf_round(x0,x1,17); tf_round(x0,x1,29); tf_round(x0,x1,16); tf_round(x0,x1,24);
  x0 += ks1; x1 += ks2 + 4u;
  tf_round(x0,x1,13); tf_round(x0,x1,15); tf_round(x0,x1,26); tf_round(x0,x1,6);
  x0 += ks2; x1 += ks0 + 5u;
  return x0 ^ x1;
}

// ================= sq[b,j] = sum_d wq[d] * Q[b,d,j] ==========================
__global__ __launch_bounds__(128) void k_sq(const float* __restrict__ Q,
                                            const float* __restrict__ W,
                                            float* __restrict__ ws) {
  const int b = blockIdx.x;
  const int j = threadIdx.x;
  const float* wq = W + (size_t)b*768;
  const float* Qb = Q + (size_t)b*ND*NLQ;
  float acc = 0.0f;
  for (int d = 0; d < ND; ++d) acc = fmaf(wq[d], Qb[(size_t)d*NLQ + j], acc);
  ws[OFF_SQ + (size_t)b*NLQ + j] = acc;
}

// ================= Q -> bf16, materialized once ==============================
__global__ __launch_bounds__(256) void k_qb(const float* __restrict__ Q,
                                            float* __restrict__ ws) {
  const size_t idx = ((size_t)blockIdx.x * 256 + threadIdx.x) * 8;
  ushort* qb = (ushort*)(ws + OFF_QB);
  const float4 a = *(const float4*)&Q[idx];
  const float4 c = *(const float4*)&Q[idx + 4];
  uint4 pk;
  pk.x = cvtpk(a.x, a.y); pk.y = cvtpk(a.z, a.w);
  pk.z = cvtpk(c.x, c.y); pk.w = cvtpk(c.z, c.w);
  *(uint4*)&qb[idx] = pk;
}

// ===== S (MFMA): fused row softmax; writes S_ bf16, S_^T bf16, u, col partials
// NO fp32 S materialization. LDS transpose tile with octet XOR swizzle
// po(i) = ((i&7)^((i>>3)&7))<<3 -> both [i][j] and [j][i] reads <=2-way.
__global__ __launch_bounds__(256) void k_s(const float* __restrict__ C,
                                           const float* __restrict__ Q,
                                           const float* __restrict__ W,
                                           float* __restrict__ ws) {
  __shared__ __align__(16) uint8_t smem[40960];
  float (*Cs)[129] = (float(*)[129])smem;                 // staging (phase 1)
  float (*Qs)[129] = (float(*)[129])(smem + 16512);
  float* wmS = (float*)(smem + 33024);
  float* wcS = (float*)(smem + 34048);
  float* sqS = (float*)(smem + 35072);                    // survives phase 2
  ushort (*T)[128]   = (ushort(*)[128])smem;              // phase 2: 32KB
  float  (*colm)[128] = (float(*)[128])(smem + 35584);
  float  (*cols)[128] = (float(*)[128])(smem + 37632);

  const int n  = blockIdx.x;
  const int rr = n & 7, qq = n >> 3;
  const int it = qq & 7;                 // member: i-tile
  const int b  = (qq >> 3) * 8 + rr;     // group: batch (same XCD)
  const int i0 = it * 128;
  const int t  = threadIdx.x;
  wcS[t] = W[(size_t)b*768 + 256 + t];
  wmS[t] = W[(size_t)b*768 + 512 + t];
  if (t < 128) sqS[t] = ws[OFF_SQ + (size_t)b*NLQ + t];

  const float* Cb = C + (size_t)b*ND*NLC;
  const float* Qb = Q + (size_t)b*ND*NLQ;
  const int l  = t & 63, w = t >> 6;
  const int lm = l & 15, lg = l >> 4;

  f32x4 acc[2][8];
  #pragma unroll
  for (int mg = 0; mg < 2; ++mg)
    #pragma unroll
    for (int nf = 0; nf < 8; ++nf) acc[mg][nf] = (f32x4)0.0f;

  for (int d0 = 0; d0 < ND; d0 += 32) {
    __syncthreads();
    #pragma unroll
    for (int p = 0; p < 4; ++p) {
      const int f  = p*256 + t;
      const int dk = f >> 5, x4 = f & 31;
      *(float4*)&Cs[dk][x4*4] = *(const float4*)&Cb[(size_t)(d0+dk)*NLC + i0 + x4*4];
      const float4 qv = *(const float4*)&Qb[(size_t)(d0+dk)*NLQ + x4*4];
      const float wmv = wmS[d0+dk], wcv = wcS[d0+dk];
      float4 o;
      o.x = fmaf(wmv, qv.x, wcv);
      o.y = fmaf(wmv, qv.y, wcv);
      o.z = fmaf(wmv, qv.z, wcv);
      o.w = fmaf(wmv, qv.w, wcv);
      *(float4*)&Qs[dk][x4*4] = o;
    }
    __syncthreads();
    bf16x8 bq[8];
    #pragma unroll
    for (int nf = 0; nf < 8; ++nf) {
      const int j = nf*16 + lm;
      union { uint32_t u[4]; bf16x8 v; } cc;
      #pragma unroll
      for (int kk = 0; kk < 4; ++kk)
        cc.u[kk] = cvtpk(Qs[lg*8 + kk*2][j], Qs[lg*8 + kk*2 + 1][j]);
      bq[nf] = cc.v;
    }
    #pragma unroll
    for (int mg = 0; mg < 2; ++mg) {
      const int i = w*32 + mg*16 + lm;
      union { uint32_t u[4]; bf16x8 v; } ca;
      #pragma unroll
      for (int kk = 0; kk < 4; ++kk)
        ca.u[kk] = cvtpk(Cs[lg*8 + kk*2][i], Cs[lg*8 + kk*2 + 1][i]);
      #pragma unroll
      for (int nf = 0; nf < 8; ++nf)
        acc[mg][nf] = __builtin_amdgcn_mfma_f32_16x16x32_bf16(ca.v, bq[nf], acc[mg][nf], 0, 0, 0);
    }
  }

  float sqv[8];
  #pragma unroll
  for (int nf = 0; nf < 8; ++nf) sqv[nf] = sqS[nf*16 + lm];
  __syncthreads();   // staging reads done; smem becomes T/colm/cols

  // --- row softmax -> T (swizzled), u write ---
  #pragma unroll
  for (int mg = 0; mg < 2; ++mg) {
    #pragma unroll
    for (int r = 0; r < 4; ++r) {
      const int row = w*32 + mg*16 + lg*4 + r;
      float sv[8], e[8];
      #pragma unroll
      for (int nf = 0; nf < 8; ++nf) sv[nf] = acc[mg][nf][r] + sqv[nf];
      float mx = sv[0];
      #pragma unroll
      for (int nf = 1; nf < 8; ++nf) mx = fmaxf(mx, sv[nf]);
      mx = fmaxf(mx, __shfl_xor(mx, 1));
      mx = fmaxf(mx, __shfl_xor(mx, 2));
      mx = fmaxf(mx, __shfl_xor(mx, 4));
      mx = fmaxf(mx, __shfl_xor(mx, 8));
      float sm = 0.0f;
      #pragma unroll
      for (int nf = 0; nf < 8; ++nf) { e[nf] = __expf(sv[nf] - mx); sm += e[nf]; }
      sm += __shfl_xor(sm, 1); sm += __shfl_xor(sm, 2);
      sm += __shfl_xor(sm, 4); sm += __shfl_xor(sm, 8);
      const float ir = 1.0f / sm;
      const int po = ((row & 7) ^ ((row >> 3) & 7)) << 3;
      #pragma unroll
      for (int nf = 0; nf < 8; ++nf)
        T[row][(nf*16 + lm) ^ po] = (ushort)f2bf(e[nf] * ir);
      if (lm == 0) ws[OFF_U + (size_t)b*NLC + i0 + row] = __expf(mx) * sm;
    }
  }

  // --- column partial stats (max then sum over this block's 128 rows) ---
  float cmx[8];
  #pragma unroll
  for (int nf = 0; nf < 8; ++nf) {
    float m2 = -3.0e38f;
    #pragma unroll
    for (int mg = 0; mg < 2; ++mg)
      #pragma unroll
      for (int r = 0; r < 4; ++r)
        m2 = fmaxf(m2, acc[mg][nf][r] + sqv[nf]);
    m2 = fmaxf(m2, __shfl_xor(m2, 16));
    m2 = fmaxf(m2, __shfl_xor(m2, 32));
    cmx[nf] = m2;
  }
  if (lg == 0) {
    #pragma unroll
    for (int nf = 0; nf < 8; ++nf) colm[w][nf*16 + lm] = cmx[nf];
  }
  __syncthreads();
  #pragma unroll
  for (int nf = 0; nf < 8; ++nf) {
    const int j = nf*16 + lm;
    const float cmb = fmaxf(fmaxf(colm[0][j], colm[1][j]),
                            fmaxf(colm[2][j], colm[3][j]));
    float cs = 0.0f;
    #pragma unroll
    for (int mg = 0; mg < 2; ++mg)
      #pragma unroll
      for (int r = 0; r < 4; ++r)
        cs += __expf(acc[mg][nf][r] + sqv[nf] - cmb);
    cs += __shfl_xor(cs, 16);
    cs += __shfl_xor(cs, 32);
    if (lg == 0) cols[w][j] = cs;
  }
  __syncthreads();

  // --- outputs: SBF rows, SBT transposed, colp partials ---
  ushort* Sb16 = (ushort*)(ws + OFF_SBF) + ((size_t)b*NLC + (size_t)i0)*NLQ;
  #pragma unroll
  for (int p = 0; p < 8; ++p) {
    const int f = p*256 + t;
    const int i = f >> 4, jo = f & 15;
    const int po = ((i & 7) ^ ((i >> 3) & 7)) << 3;
    *(uint4*)&Sb16[(size_t)i*NLQ + jo*8] = *(const uint4*)&T[i][(jo*8) ^ po];
  }
  ushort* SBTg = (ushort*)(ws + OFF_SBT) + (size_t)b*NLQ*NLC + i0;
  #pragma unroll
  for (int p = 0; p < 8; ++p) {
    const int f = p*256 + t;
    const int j = f >> 4, io = f & 15;
    uint32_t wd4[4];
    #pragma unroll
    for (int h = 0; h < 4; ++h) {
      const uint32_t v0 = T[io*8 + h*2    ][j ^ (((h*2    ) ^ (io & 7)) << 3)];
      const uint32_t v1 = T[io*8 + h*2 + 1][j ^ (((h*2 + 1) ^ (io & 7)) << 3)];
      wd4[h] = v0 | (v1 << 16);
    }
    *(uint4*)&SBTg[(size_t)j*NLC + io*8] = *(uint4*)wd4;
  }
  if (t < 128) {
    const float cm = fmaxf(fmaxf(colm[0][t], colm[1][t]),
                           fmaxf(colm[2][t], colm[3][t]));
    const float s  = cols[0][t] + cols[1][t] + cols[2][t] + cols[3][t];
    float2* cp = (float2*)(ws + OFF_COLP) + ((size_t)b*8 + it)*128 + t;
    *cp = make_float2(cm, s);
  }
}

// ===== merge col partials -> v(j) = exp(-cmax)/colsum ========================
__global__ __launch_bounds__(128) void k_cred(float* __restrict__ ws) {
  const int b = blockIdx.x, j = threadIdx.x;
  const float2* cp = (const float2*)(ws + OFF_COLP) + (size_t)b*8*128 + j;
  float m = -3.0e38f, s = 0.0f;
  #pragma unroll
  for (int it = 0; it < 8; ++it) {
    const float2 p = cp[(size_t)it*128];
    const float nm = fmaxf(m, p.x);
    s = s * __expf(m - nm) + p.y * __expf(p.x - nm);
    m = nm;
  }
  ws[OFF_V + (size_t)b*NLQ + j] = __expf(-m) / s;
}

// ===== M (MFMA): M[d,j] = v(j) * sum_k (C[d,k]*u(k)) * S_[k,j] ==============
// A = C*u bf16 (tiny staging); B = S_^T pure uint4 copies. No exp in loop.
__global__ __launch_bounds__(256) void k_m(const float* __restrict__ C,
                                           float* __restrict__ ws) {
  __shared__ ushort Cp[32][40];
  __shared__ ushort Ts[128][40];
  __shared__ float u_l[1024];
  __shared__ float v_l[128];
  const int n  = blockIdx.x;
  const int rr = n & 7, qq = n >> 3;
  const int dq = qq & 7;                // member: d-tile (32 rows)
  const int b  = (qq >> 3) * 8 + rr;    // group: batch (same XCD)
  const int t  = threadIdx.x;
  const int l  = t & 63, w = t >> 6;
  const int wd = w & 1, wj = w >> 1;
  const int lm = l & 15, lg = l >> 4;
  for (int kk = t; kk < 1024; kk += 256) u_l[kk] = ws[OFF_U + (size_t)b*NLC + kk];
  if (t < 128) v_l[t] = ws[OFF_V + (size_t)b*NLQ + t];

  f32x4 acc[4];
  #pragma unroll
  for (int nf = 0; nf < 4; ++nf) acc[nf] = (f32x4)0.0f;

  const float*  Cb   = C + (size_t)b*ND*NLC + (size_t)dq*32*NLC;
  const ushort* SBTg = (const ushort*)(ws + OFF_SBT) + (size_t)b*NLQ*NLC;

  for (int kt = 0; kt < 32; ++kt) {
    const int k0 = kt*32;
    __syncthreads();
    {                                    // stage C' = C*u (32d x 32k)
      const int dl = t >> 3, kq = t & 7;
      const float4 cv = *(const float4*)&Cb[(size_t)dl*NLC + k0 + kq*4];
      const int kb = k0 + kq*4;
      uint2 pk;
      pk.x = cvtpk(cv.x * u_l[kb+0], cv.y * u_l[kb+1]);
      pk.y = cvtpk(cv.z * u_l[kb+2], cv.w * u_l[kb+3]);
      *(uint2*)&Cp[dl][kq*4] = pk;
    }
    #pragma unroll
    for (int p = 0; p < 2; ++p) {        // stage S_^T tile (128j x 32k) copies
      const int f = p*256 + t;
      const int jr = f >> 2, k8 = (f & 3)*8;
      *(uint4*)&Ts[jr][k8] = *(const uint4*)&SBTg[(size_t)jr*NLC + k0 + k8];
    }
    __syncthreads();
    union { uint32_t u[4]; bf16x8 v; } ca;
    *(uint4*)ca.u = *(const uint4*)&Cp[wd*16 + lm][lg*8];
    #pragma unroll
    for (int nf = 0; nf < 4; ++nf) {
      union { uint32_t u[4]; bf16x8 v; } cb;
      *(uint4*)cb.u = *(const uint4*)&Ts[wj*64 + nf*16 + lm][lg*8];
      acc[nf] = __builtin_amdgcn_mfma_f32_16x16x32_bf16(ca.v, cb.v, acc[nf], 0, 0, 0);
    }
  }
  ushort* Mp = (ushort*)(ws + OFF_M) + (size_t)b*ND*NLQ + (size_t)dq*32*NLQ;
  #pragma unroll
  for (int nf = 0; nf < 4; ++nf) {
    const int j = wj*64 + nf*16 + lm;
    const float vj = v_l[j];
    #pragma unroll
    for (int r = 0; r < 4; ++r) {
      const int d = wd*16 + lg*4 + r;
      Mp[(size_t)d*NLQ + j] = (ushort)f2bf(acc[nf][r] * vj);
    }
  }
}

// ==== final (MFMA): A = Q*S_^T, Bm = M*S_^T, out = [C, A, C*A, C*Bm] ========
// d-tile 16 -> LDS 40KB -> 4 blocks/CU (16 waves). Grid 8192 = 16 d-blocks
// x 512 (i0,b) groups (round-10 bug: grid was 4096, half of i never written).
__global__ __launch_bounds__(256, 4) void k_final(const float* __restrict__ C,
                                                  float* __restrict__ ws,
                                                  float* __restrict__ out) {
  __shared__ __align__(16) uint8_t smem[40960];
  ushort (*St)[128] = (ushort(*)[128])smem;            // [i 128][j 128] 32KB
  ushort (*Qt)[128] = (ushort(*)[128])(smem + 32768);  // [d 16][j 128]  4KB
  ushort (*Mt)[128] = (ushort(*)[128])(smem + 36864);  // [d 16][j 128]  4KB
  float  (*At)[128] = (float (*)[128])smem;            // epilogue [d 16][i 128]
  float  (*Bt)[128] = (float (*)[128])(smem + 8192);

  const int n  = blockIdx.x;
  const int r8 = n & 7, q = n >> 3;       // q in 0..1023
  const int m  = q & 15;                  // member: d0 block (16 rows)
  const int g  = (q >> 4) * 8 + r8;       // group 0..511 = (i0, b), one XCD
  const int b  = g & 63;
  const int i0 = (g >> 6) * 128;
  const int d0 = m * 16;
  const int t  = threadIdx.x;

  const ushort* Sp = (const ushort*)(ws + OFF_SBF) + ((size_t)b*NLC + i0)*NLQ;
  #pragma unroll
  for (int p = 0; p < 8; ++p) {         // S_ bf16: swizzled uint4 copies
    const int f  = p*256 + t;
    const int jo = f & 15;
    const int il = f >> 4;
    *(uint4*)&St[il][(jo*8) ^ ((il & 7) << 3)] =
        *(const uint4*)&Sp[(size_t)il*NLQ + jo*8];
  }
  const ushort* Qp = (const ushort*)(ws + OFF_QB) + (size_t)b*ND*NLQ + (size_t)d0*NLQ;
  const ushort* Mp = (const ushort*)(ws + OFF_M)  + (size_t)b*ND*NLQ + (size_t)d0*NLQ;
  {                                     // Q/M bf16: swizzled uint4 copies
    const int jo = t & 15;
    const int dl = t >> 4;
    const int col = (jo*8) ^ ((dl & 7) << 3);
    *(uint4*)&Qt[dl][col] = *(const uint4*)&Qp[(size_t)dl*NLQ + jo*8];
    *(uint4*)&Mt[dl][col] = *(const uint4*)&Mp[(size_t)dl*NLQ + jo*8];
  }
  __syncthreads();

  const int w  = t >> 6;
  const int l  = t & 63;
  const int lm = l & 15;
  const int lk = (l >> 4) * 8;
  const int sw = (lm & 7) << 3;

  f32x4 accA[2], accB[2];
  #pragma unroll
  for (int f = 0; f < 2; ++f) { accA[f] = (f32x4)0.0f; accB[f] = (f32x4)0.0f; }

  #pragma unroll
  for (int ks = 0; ks < 4; ++ks) {
    const int koff = (ks*32 + lk) ^ sw;
    const bf16x8 qf = *(const bf16x8*)&Qt[lm][koff];
    const bf16x8 mf = *(const bf16x8*)&Mt[lm][koff];
    #pragma unroll
    for (int f = 0; f < 2; ++f) {
      const bf16x8 sf = *(const bf16x8*)&St[(w*2 + f)*16 + lm][koff];
      accA[f] = __builtin_amdgcn_mfma_f32_16x16x32_bf16(qf, sf, accA[f], 0, 0, 0);
      accB[f] = __builtin_amdgcn_mfma_f32_16x16x32_bf16(mf, sf, accB[f], 0, 0, 0);
    }
  }
  __syncthreads();   // staging buffers dead; reuse as At/Bt

  const int dwl = (l >> 4) * 4;
  #pragma unroll
  for (int f = 0; f < 2; ++f) {
    const int i = (w*2 + f)*16 + lm;
    #pragma unroll
    for (int r = 0; r < 4; ++r) {
      const int dl = dwl + r;
      const int isw = i ^ ((dl & 7) << 2);
      At[dl][isw] = accA[f][r];
      Bt[dl][isw] = accB[f][r];
    }
  }
  __syncthreads();

  const int il4 = (t & 31) * 4;
  const int dg8 = t >> 5;
  const float* Cb = C + (size_t)b*ND*NLC;
  #pragma unroll 1
  for (int dd = 0; dd < 2; ++dd) {
    const int dl = dd*8 + dg8;
    const int d  = d0 + dl;
    const int isw = il4 ^ ((dl & 7) << 2);
    const float4 a4 = *(const float4*)&At[dl][isw];
    const float4 b4 = *(const float4*)&Bt[dl][isw];
    const float4 c4 = *(const float4*)&Cb[(size_t)d*NLC + i0 + il4];
    const float av[4] = {a4.x, a4.y, a4.z, a4.w};
    const float bv[4] = {b4.x, b4.y, b4.z, b4.w};
    const float cv[4] = {c4.x, c4.y, c4.z, c4.w};
    #pragma unroll
    for (int s = 0; s < 4; ++s) {
      const uint32_t nb = ((((uint32_t)b << 10) + (uint32_t)(s*ND + d)) << 10)
                          + (uint32_t)(i0 + il4);
      float ov[4];
      #pragma unroll
      for (int e = 0; e < 4; ++e) {
        const uint32_t bits = threefry_xor(0u, nb + (uint32_t)e);
        float v;
        if (s == 0)      v = cv[e];
        else if (s == 1) v = av[e];
        else if (s == 2) v = cv[e] * av[e];
        else             v = cv[e] * bv[e];
        ov[e] = ((bits >> 9) < 7549747u) ? v * INVKEEP : 0.0f;
      }
      *(float4*)&out[nb] = make_float4(ov[0], ov[1], ov[2], ov[3]);
    }
  }
}

extern "C" void kernel_launch(void* const* d_in, const int* in_sizes, int n_in,
                              void* d_out, int out_size, void* d_ws, size_t ws_size,
                              hipStream_t stream) {
  (void)in_sizes; (void)n_in; (void)out_size; (void)ws_size;
  const float* C = (const float*)d_in[0];
  const float* Q = (const float*)d_in[1];
  const float* W = (const float*)d_in[2];
  float* out = (float*)d_out;
  float* ws  = (float*)d_ws;

  hipLaunchKernelGGL(k_sq,    dim3(NB),   dim3(128), 0, stream, Q, W, ws);
  hipLaunchKernelGGL(k_qb,    dim3(1024), dim3(256), 0, stream, Q, ws);
  hipLaunchKernelGGL(k_s,     dim3(512),  dim3(256), 0, stream, C, Q, W, ws);
  hipLaunchKernelGGL(k_cred,  dim3(NB),   dim3(128), 0, stream, ws);
  hipLaunchKernelGGL(k_m,     dim3(512),  dim3(256), 0, stream, C, ws);
  hipLaunchKernelGGL(k_final, dim3(8192), dim3(256), 0, stream, C, ws, out);
}

// Round 12
// 181.964 us; speedup vs baseline: 2.4873x; 1.1949x over previous
//
#include <hip/hip_runtime.h>
#include <stdint.h>
#include <stddef.h>

#define NB  64
#define ND  256
#define NLC 1024
#define NLQ 128
#define INVKEEP (1.0f/0.9f)

// ---- workspace layout (float offsets); total 14,835,712 floats = 56.6 MiB ----
#define OFF_SQP   0u            // NB*4*128   sq partials (4 chunks)
#define OFF_U     32768u        // NB*NLC     u(i) = exp(rmax_i)*rowsum_i
#define OFF_V     98304u        // NB*NLQ     v(j) = exp(-cmax_j)/colsum_j
#define OFF_COLP  106496u       // NB*8*128*2 col partials (m,s)
#define OFF_SBT   237568u       // NB*NLQ*NLC bf16 S_^T
#define OFF_QT    4431872u      // NB*NLQ*ND  bf16 Q'^T (wm*Q+wc, [j][d])
#define OFF_SBF   8544256u      // NB*NLC*NLQ bf16 S_
#define OFF_M     12738560u     // NB*ND*NLQ  bf16 M
#define OFF_QB    13787136u     // NB*ND*NLQ  bf16 Q

typedef float f32x4  __attribute__((ext_vector_type(4)));
typedef short bf16x8 __attribute__((ext_vector_type(8)));

__device__ __forceinline__ uint32_t f2bf(float x) {
  const uint32_t u = __float_as_uint(x);
  return (u + 0x7fffu + ((u >> 16) & 1u)) >> 16;
}
__device__ __forceinline__ uint32_t cvtpk(float lo, float hi) {
  uint32_t r;
  asm("v_cvt_pk_bf16_f32 %0, %1, %2" : "=v"(r) : "v"(lo), "v"(hi));
  return r;
}

// ================= threefry2x32, key=(0,42); bits = o0^o1 (verified r2) =====
__device__ __forceinline__ void tf_round(uint32_t& a, uint32_t& b, const int r) {
  a += b;
  b = (b << r) | (b >> (32 - r));
  b ^= a;
}
__device__ __forceinline__ uint32_t threefry_xor(uint32_t x0, uint32_t x1) {
  const uint32_t ks0 = 0u, ks1 = 42u, ks2 = 0x1BD11BDAu ^ 0u ^ 42u;
  x0 += ks0; x1 += ks1;
  tf_round(x0,x1,13); tf_round(x0,x1,15); tf_round(x0,x1,26); tf_round(x0,x1,6);
  x0 += ks1; x1 += ks2 + 1u;
  tf_round(x0,x1,17); tf_round(x0,x1,29); tf_round(x0,x1,16); tf_round(x0,x1,24);
  x0 += ks2; x1 += ks0 + 2u;
  tf_round(x0,x1,13); tf_round(x0,x1,15); tf_round(x0,x1,26); tf_round(x0,x1,6);
  x0 += ks0; x1 += ks1 + 3u;
  tf_round(x0,x1,17); tf_round(x0,x1,29); tf_round(x0,x1,16); tf_round(x0,x1,24);
  x0 += ks1; x1 += ks2 + 4u;
  tf_round(x0,x1,13); tf_round(x0,x1,15); tf_round(x0,x1,26); tf_round(x0,x1,6);
  x0 += ks2; x1 += ks0 + 5u;
  return x0 ^ x1;
}

// ===== prep: Q -> QB bf16 [d][j], Q'^T bf16 [j][d], sq partials ==============
// grid 256 = (b, chunk c of 64 d). Same rounding points as before.
__global__ __launch_bounds__(256) void k_prep(const float* __restrict__ Q,
                                              const float* __restrict__ W,
                                              float* __restrict__ ws) {
  __shared__ __align__(16) float Qs[64][129];
  __shared__ float wqS[64], wmS[64], wcS[64];
  __shared__ float red[8][128];
  const int n = blockIdx.x;
  const int b = n >> 2, c = n & 3;
  const int d0 = c * 64;
  const int t = threadIdx.x;
  if (t < 64) {
    wqS[t] = W[(size_t)b*768 + d0 + t];
    wcS[t] = W[(size_t)b*768 + 256 + d0 + t];
    wmS[t] = W[(size_t)b*768 + 512 + d0 + t];
  }
  __syncthreads();
  const float* Qb = Q + (size_t)b*ND*NLQ;
  ushort* QBg = (ushort*)(ws + OFF_QB) + (size_t)b*ND*NLQ;
  const int j4 = t & 31, y = t >> 5;
  float sq4[4] = {0.0f, 0.0f, 0.0f, 0.0f};
  #pragma unroll
  for (int p = 0; p < 8; ++p) {
    const int dk = p*8 + y;
    const float4 qv = *(const float4*)&Qb[(size_t)(d0+dk)*NLQ + j4*4];
    *(float4*)&Qs[dk][j4*4] = qv;
    uint2 pk;
    pk.x = cvtpk(qv.x, qv.y);
    pk.y = cvtpk(qv.z, qv.w);
    *(uint2*)&QBg[(size_t)(d0+dk)*NLQ + j4*4] = pk;
    const float wq = wqS[dk];
    sq4[0] = fmaf(wq, qv.x, sq4[0]);
    sq4[1] = fmaf(wq, qv.y, sq4[1]);
    sq4[2] = fmaf(wq, qv.z, sq4[2]);
    sq4[3] = fmaf(wq, qv.w, sq4[3]);
  }
  #pragma unroll
  for (int e = 0; e < 4; ++e) red[y][j4*4 + e] = sq4[e];
  __syncthreads();
  // Q'^T phase: thread owns (j = t>>1, half dh)
  const int j = t >> 1, dh = (t & 1) * 32;
  uint32_t pk16[16];
  #pragma unroll
  for (int kk = 0; kk < 32; kk += 2) {
    const float q0 = fmaf(wmS[dh+kk],   Qs[dh+kk][j],   wcS[dh+kk]);
    const float q1 = fmaf(wmS[dh+kk+1], Qs[dh+kk+1][j], wcS[dh+kk+1]);
    pk16[kk >> 1] = cvtpk(q0, q1);
  }
  ushort* QTg = (ushort*)(ws + OFF_QT) + (size_t)b*NLQ*ND + (size_t)j*ND + d0 + dh;
  *(uint4*)&QTg[0]  = *(uint4*)&pk16[0];
  *(uint4*)&QTg[8]  = *(uint4*)&pk16[4];
  *(uint4*)&QTg[16] = *(uint4*)&pk16[8];
  *(uint4*)&QTg[24] = *(uint4*)&pk16[12];
  if (t < 128) {
    float s = 0.0f;
    #pragma unroll
    for (int yy = 0; yy < 8; ++yy) s += red[yy][t];
    ws[OFF_SQP + ((size_t)b*4 + c)*128 + t] = s;
  }
}

// ===== S (MFMA): fused row softmax; writes S_ bf16, S_^T bf16, u, col partials
// A-frags: fp32 C columns + cvtpk. B-frags: single b128 reads from Q'^T tile.
__global__ __launch_bounds__(256) void k_s(const float* __restrict__ C,
                                           float* __restrict__ ws) {
  __shared__ __align__(16) uint8_t smem[37376];
  float  (*Cs)[129] = (float(*)[129])smem;                // [d 32][i 128] fp32
  ushort (*Qt)[40]  = (ushort(*)[40])(smem + 16512);      // [j 128][d 32] bf16
  ushort (*T)[128]  = (ushort(*)[128])smem;               // phase2: 32KB
  float*  sqS       = (float*)(smem + 32768);             // 128 f (safe zone)
  float  (*colm)[128] = (float(*)[128])(smem + 33280);
  float  (*cols)[128] = (float(*)[128])(smem + 35328);

  const int n  = blockIdx.x;
  const int rr = n & 7, qq = n >> 3;
  const int it = qq & 7;                 // member: i-tile
  const int b  = (qq >> 3) * 8 + rr;     // group: batch (same XCD)
  const int i0 = it * 128;
  const int t  = threadIdx.x;
  if (t < 128) {
    const float* sp = ws + OFF_SQP + (size_t)b*4*128 + t;
    sqS[t] = sp[0] + sp[128] + sp[256] + sp[384];
  }

  const float*  Cb  = C + (size_t)b*ND*NLC;
  const ushort* QTg = (const ushort*)(ws + OFF_QT) + (size_t)b*NLQ*ND;
  const int l  = t & 63, w = t >> 6;
  const int lm = l & 15, lg = l >> 4;

  f32x4 acc[2][8];
  #pragma unroll
  for (int mg = 0; mg < 2; ++mg)
    #pragma unroll
    for (int nf = 0; nf < 8; ++nf) acc[mg][nf] = (f32x4)0.0f;

  for (int d0 = 0; d0 < ND; d0 += 32) {
    __syncthreads();
    #pragma unroll
    for (int p = 0; p < 4; ++p) {        // stage C tile fp32 (coalesced)
      const int f  = p*256 + t;
      const int dk = f >> 5, x4 = f & 31;
      *(float4*)&Cs[dk][x4*4] = *(const float4*)&Cb[(size_t)(d0+dk)*NLC + i0 + x4*4];
    }
    #pragma unroll
    for (int p = 0; p < 2; ++p) {        // stage Q'^T tile: pure uint4 copies
      const int f  = p*256 + t;
      const int jr = f >> 2, k8 = (f & 3)*8;
      *(uint4*)&Qt[jr][k8] = *(const uint4*)&QTg[(size_t)jr*ND + d0 + k8];
    }
    __syncthreads();
    bf16x8 bq[8];
    #pragma unroll
    for (int nf = 0; nf < 8; ++nf)       // B-frags: one b128 each
      bq[nf] = *(const bf16x8*)&Qt[nf*16 + lm][lg*8];
    #pragma unroll
    for (int mg = 0; mg < 2; ++mg) {
      const int i = w*32 + mg*16 + lm;
      union { uint32_t u[4]; bf16x8 v; } ca;
      #pragma unroll
      for (int kk = 0; kk < 4; ++kk)
        ca.u[kk] = cvtpk(Cs[lg*8 + kk*2][i], Cs[lg*8 + kk*2 + 1][i]);
      #pragma unroll
      for (int nf = 0; nf < 8; ++nf)
        acc[mg][nf] = __builtin_amdgcn_mfma_f32_16x16x32_bf16(ca.v, bq[nf], acc[mg][nf], 0, 0, 0);
    }
  }

  float sqv[8];
  #pragma unroll
  for (int nf = 0; nf < 8; ++nf) sqv[nf] = sqS[nf*16 + lm];
  __syncthreads();   // staging dead; smem becomes T/colm/cols

  // --- row softmax -> T (swizzled), u write ---
  #pragma unroll
  for (int mg = 0; mg < 2; ++mg) {
    #pragma unroll
    for (int r = 0; r < 4; ++r) {
      const int row = w*32 + mg*16 + lg*4 + r;
      float sv[8], e[8];
      #pragma unroll
      for (int nf = 0; nf < 8; ++nf) sv[nf] = acc[mg][nf][r] + sqv[nf];
      float mx = sv[0];
      #pragma unroll
      for (int nf = 1; nf < 8; ++nf) mx = fmaxf(mx, sv[nf]);
      mx = fmaxf(mx, __shfl_xor(mx, 1));
      mx = fmaxf(mx, __shfl_xor(mx, 2));
      mx = fmaxf(mx, __shfl_xor(mx, 4));
      mx = fmaxf(mx, __shfl_xor(mx, 8));
      float sm = 0.0f;
      #pragma unroll
      for (int nf = 0; nf < 8; ++nf) { e[nf] = __expf(sv[nf] - mx); sm += e[nf]; }
      sm += __shfl_xor(sm, 1); sm += __shfl_xor(sm, 2);
      sm += __shfl_xor(sm, 4); sm += __shfl_xor(sm, 8);
      const float ir = 1.0f / sm;
      const int po = ((row & 7) ^ ((row >> 3) & 7)) << 3;
      #pragma unroll
      for (int nf = 0; nf < 8; ++nf)
        T[row][(nf*16 + lm) ^ po] = (ushort)f2bf(e[nf] * ir);
      if (lm == 0) ws[OFF_U + (size_t)b*NLC + i0 + row] = __expf(mx) * sm;
    }
  }

  // --- column partial stats ---
  float cmx[8];
  #pragma unroll
  for (int nf = 0; nf < 8; ++nf) {
    float m2 = -3.0e38f;
    #pragma unroll
    for (int mg = 0; mg < 2; ++mg)
      #pragma unroll
      for (int r = 0; r < 4; ++r)
        m2 = fmaxf(m2, acc[mg][nf][r] + sqv[nf]);
    m2 = fmaxf(m2, __shfl_xor(m2, 16));
    m2 = fmaxf(m2, __shfl_xor(m2, 32));
    cmx[nf] = m2;
  }
  if (lg == 0) {
    #pragma unroll
    for (int nf = 0; nf < 8; ++nf) colm[w][nf*16 + lm] = cmx[nf];
  }
  __syncthreads();
  #pragma unroll
  for (int nf = 0; nf < 8; ++nf) {
    const int j = nf*16 + lm;
    const float cmb = fmaxf(fmaxf(colm[0][j], colm[1][j]),
                            fmaxf(colm[2][j], colm[3][j]));
    float cs = 0.0f;
    #pragma unroll
    for (int mg = 0; mg < 2; ++mg)
      #pragma unroll
      for (int r = 0; r < 4; ++r)
        cs += __expf(acc[mg][nf][r] + sqv[nf] - cmb);
    cs += __shfl_xor(cs, 16);
    cs += __shfl_xor(cs, 32);
    if (lg == 0) cols[w][j] = cs;
  }
  __syncthreads();

  // --- outputs: SBF rows, SBT transposed, colp partials ---
  ushort* Sb16 = (ushort*)(ws + OFF_SBF) + ((size_t)b*NLC + (size_t)i0)*NLQ;
  #pragma unroll
  for (int p = 0; p < 8; ++p) {
    const int f = p*256 + t;
    const int i = f >> 4, jo = f & 15;
    const int po = ((i & 7) ^ ((i >> 3) & 7)) << 3;
    *(uint4*)&Sb16[(size_t)i*NLQ + jo*8] = *(const uint4*)&T[i][(jo*8) ^ po];
  }
  ushort* SBTg = (ushort*)(ws + OFF_SBT) + (size_t)b*NLQ*NLC + i0;
  #pragma unroll
  for (int p = 0; p < 8; ++p) {
    const int f = p*256 + t;
    const int j = f >> 4, io = f & 15;
    uint32_t wd4[4];
    #pragma unroll
    for (int h = 0; h < 4; ++h) {
      const uint32_t v0 = T[io*8 + h*2    ][j ^ (((h*2    ) ^ (io & 7)) << 3)];
      const uint32_t v1 = T[io*8 + h*2 + 1][j ^ (((h*2 + 1) ^ (io & 7)) << 3)];
      wd4[h] = v0 | (v1 << 16);
    }
    *(uint4*)&SBTg[(size_t)j*NLC + io*8] = *(uint4*)wd4;
  }
  if (t < 128) {
    const float cm = fmaxf(fmaxf(colm[0][t], colm[1][t]),
                           fmaxf(colm[2][t], colm[3][t]));
    const float s  = cols[0][t] + cols[1][t] + cols[2][t] + cols[3][t];
    float2* cp = (float2*)(ws + OFF_COLP) + ((size_t)b*8 + it)*128 + t;
    *cp = make_float2(cm, s);
  }
}

// ===== merge col partials -> v(j) = exp(-cmax)/colsum ========================
__global__ __launch_bounds__(128) void k_cred(float* __restrict__ ws) {
  const int b = blockIdx.x, j = threadIdx.x;
  const float2* cp = (const float2*)(ws + OFF_COLP) + (size_t)b*8*128 + j;
  float m = -3.0e38f, s = 0.0f;
  #pragma unroll
  for (int it = 0; it < 8; ++it) {
    const float2 p = cp[(size_t)it*128];
    const float nm = fmaxf(m, p.x);
    s = s * __expf(m - nm) + p.y * __expf(p.x - nm);
    m = nm;
  }
  ws[OFF_V + (size_t)b*NLQ + j] = __expf(-m) / s;
}

// ===== M (MFMA): M[d,j] = v(j) * sum_k (C[d,k]*u(k)) * S_[k,j], K-step 64 ===
__global__ __launch_bounds__(256) void k_m(const float* __restrict__ C,
                                           float* __restrict__ ws) {
  __shared__ ushort Cp[32][72];
  __shared__ ushort Ts[128][72];
  __shared__ float u_l[1024];
  __shared__ float v_l[128];
  const int n  = blockIdx.x;
  const int rr = n & 7, qq = n >> 3;
  const int dq = qq & 7;                // member: d-tile (32 rows)
  const int b  = (qq >> 3) * 8 + rr;    // group: batch (same XCD)
  const int t  = threadIdx.x;
  const int l  = t & 63, w = t >> 6;
  const int wd = w & 1, wj = w >> 1;
  const int lm = l & 15, lg = l >> 4;
  for (int kk = t; kk < 1024; kk += 256) u_l[kk] = ws[OFF_U + (size_t)b*NLC + kk];
  if (t < 128) v_l[t] = ws[OFF_V + (size_t)b*NLQ + t];

  f32x4 acc[4];
  #pragma unroll
  for (int nf = 0; nf < 4; ++nf) acc[nf] = (f32x4)0.0f;

  const float*  Cb   = C + (size_t)b*ND*NLC + (size_t)dq*32*NLC;
  const ushort* SBTg = (const ushort*)(ws + OFF_SBT) + (size_t)b*NLQ*NLC;

  for (int kt = 0; kt < 16; ++kt) {
    const int k0 = kt*64;
    __syncthreads();
    {                                    // stage C' = C*u (32 d x 64 k)
      const int dl = t >> 3, kq = t & 7;
      const float4 c0 = *(const float4*)&Cb[(size_t)dl*NLC + k0 + kq*8];
      const float4 c1 = *(const float4*)&Cb[(size_t)dl*NLC + k0 + kq*8 + 4];
      const int kb = k0 + kq*8;
      uint4 pk;
      pk.x = cvtpk(c0.x * u_l[kb+0], c0.y * u_l[kb+1]);
      pk.y = cvtpk(c0.z * u_l[kb+2], c0.w * u_l[kb+3]);
      pk.z = cvtpk(c1.x * u_l[kb+4], c1.y * u_l[kb+5]);
      pk.w = cvtpk(c1.z * u_l[kb+6], c1.w * u_l[kb+7]);
      *(uint4*)&Cp[dl][kq*8] = pk;
    }
    #pragma unroll
    for (int p = 0; p < 4; ++p) {        // stage S_^T tile (128 j x 64 k)
      const int f = p*256 + t;
      const int jr = f >> 3, k8 = (f & 7)*8;
      *(uint4*)&Ts[jr][k8] = *(const uint4*)&SBTg[(size_t)jr*NLC + k0 + k8];
    }
    __syncthreads();
    #pragma unroll
    for (int ks = 0; ks < 2; ++ks) {
      union { uint32_t u[4]; bf16x8 v; } ca;
      *(uint4*)ca.u = *(const uint4*)&Cp[wd*16 + lm][ks*32 + lg*8];
      #pragma unroll
      for (int nf = 0; nf < 4; ++nf) {
        union { uint32_t u[4]; bf16x8 v; } cb;
        *(uint4*)cb.u = *(const uint4*)&Ts[wj*64 + nf*16 + lm][ks*32 + lg*8];
        acc[nf] = __builtin_amdgcn_mfma_f32_16x16x32_bf16(ca.v, cb.v, acc[nf], 0, 0, 0);
      }
    }
  }
  ushort* Mp = (ushort*)(ws + OFF_M) + (size_t)b*ND*NLQ + (size_t)dq*32*NLQ;
  #pragma unroll
  for (int nf = 0; nf < 4; ++nf) {
    const int j = wj*64 + nf*16 + lm;
    const float vj = v_l[j];
    #pragma unroll
    for (int r = 0; r < 4; ++r) {
      const int d = wd*16 + lg*4 + r;
      Mp[(size_t)d*NLQ + j] = (ushort)f2bf(acc[nf][r] * vj);
    }
  }
}

// ==== final (MFMA): A = Q*S_^T, Bm = M*S_^T, out = [C, A, C*A, C*Bm] ========
__global__ __launch_bounds__(256, 4) void k_final(const float* __restrict__ C,
                                                  float* __restrict__ ws,
                                                  float* __restrict__ out) {
  __shared__ __align__(16) uint8_t smem[40960];
  ushort (*St)[128] = (ushort(*)[128])smem;            // [i 128][j 128] 32KB
  ushort (*Qt)[128] = (ushort(*)[128])(smem + 32768);  // [d 16][j 128]  4KB
  ushort (*Mt)[128] = (ushort(*)[128])(smem + 36864);  // [d 16][j 128]  4KB
  float  (*At)[128] = (float (*)[128])smem;            // epilogue [d 16][i 128]
  float  (*Bt)[128] = (float (*)[128])(smem + 8192);

  const int n  = blockIdx.x;
  const int r8 = n & 7, q = n >> 3;       // q in 0..1023
  const int m  = q & 15;                  // member: d0 block (16 rows)
  const int g  = (q >> 4) * 8 + r8;       // group 0..511 = (i0, b), one XCD
  const int b  = g & 63;
  const int i0 = (g >> 6) * 128;
  const int d0 = m * 16;
  const int t  = threadIdx.x;

  const ushort* Sp = (const ushort*)(ws + OFF_SBF) + ((size_t)b*NLC + i0)*NLQ;
  #pragma unroll
  for (int p = 0; p < 8; ++p) {         // S_ bf16: swizzled uint4 copies
    const int f  = p*256 + t;
    const int jo = f & 15;
    const int il = f >> 4;
    *(uint4*)&St[il][(jo*8) ^ ((il & 7) << 3)] =
        *(const uint4*)&Sp[(size_t)il*NLQ + jo*8];
  }
  const ushort* Qp = (const ushort*)(ws + OFF_QB) + (size_t)b*ND*NLQ + (size_t)d0*NLQ;
  const ushort* Mp = (const ushort*)(ws + OFF_M)  + (size_t)b*ND*NLQ + (size_t)d0*NLQ;
  {                                     // Q/M bf16: swizzled uint4 copies
    const int jo = t & 15;
    const int dl = t >> 4;
    const int col = (jo*8) ^ ((dl & 7) << 3);
    *(uint4*)&Qt[dl][col] = *(const uint4*)&Qp[(size_t)dl*NLQ + jo*8];
    *(uint4*)&Mt[dl][col] = *(const uint4*)&Mp[(size_t)dl*NLQ + jo*8];
  }
  __syncthreads();

  const int w  = t >> 6;
  const int l  = t & 63;
  const int lm = l & 15;
  const int lk = (l >> 4) * 8;
  const int sw = (lm & 7) << 3;

  f32x4 accA[2], accB[2];
  #pragma unroll
  for (int f = 0; f < 2; ++f) { accA[f] = (f32x4)0.0f; accB[f] = (f32x4)0.0f; }

  #pragma unroll
  for (int ks = 0; ks < 4; ++ks) {
    const int koff = (ks*32 + lk) ^ sw;
    const bf16x8 qf = *(const bf16x8*)&Qt[lm][koff];
    const bf16x8 mf = *(const bf16x8*)&Mt[lm][koff];
    #pragma unroll
    for (int f = 0; f < 2; ++f) {
      const bf16x8 sf = *(const bf16x8*)&St[(w*2 + f)*16 + lm][koff];
      accA[f] = __builtin_amdgcn_mfma_f32_16x16x32_bf16(qf, sf, accA[f], 0, 0, 0);
      accB[f] = __builtin_amdgcn_mfma_f32_16x16x32_bf16(mf, sf, accB[f], 0, 0, 0);
    }
  }
  __syncthreads();   // staging buffers dead; reuse as At/Bt

  const int dwl = (l >> 4) * 4;
  #pragma unroll
  for (int f = 0; f < 2; ++f) {
    const int i = (w*2 + f)*16 + lm;
    #pragma unroll
    for (int r = 0; r < 4; ++r) {
      const int dl = dwl + r;
      const int isw = i ^ ((dl & 7) << 2);
      At[dl][isw] = accA[f][r];
      Bt[dl][isw] = accB[f][r];
    }
  }
  __syncthreads();

  const int il4 = (t & 31) * 4;
  const int dg8 = t >> 5;
  const float* Cb = C + (size_t)b*ND*NLC;
  #pragma unroll 1
  for (int dd = 0; dd < 2; ++dd) {
    const int dl = dd*8 + dg8;
    const int d  = d0 + dl;
    const int isw = il4 ^ ((dl & 7) << 2);
    const float4 a4 = *(const float4*)&At[dl][isw];
    const float4 b4 = *(const float4*)&Bt[dl][isw];
    const float4 c4 = *(const float4*)&Cb[(size_t)d*NLC + i0 + il4];
    const float av[4] = {a4.x, a4.y, a4.z, a4.w};
    const float bv[4] = {b4.x, b4.y, b4.z, b4.w};
    const float cv[4] = {c4.x, c4.y, c4.z, c4.w};
    #pragma unroll
    for (int s = 0; s < 4; ++s) {
      const uint32_t nb = ((((uint32_t)b << 10) + (uint32_t)(s*ND + d)) << 10)
                          + (uint32_t)(i0 + il4);
      float ov[4];
      #pragma unroll
      for (int e = 0; e < 4; ++e) {
        const uint32_t bits = threefry_xor(0u, nb + (uint32_t)e);
        float v;
        if (s == 0)      v = cv[e];
        else if (s == 1) v = av[e];
        else if (s == 2) v = cv[e] * av[e];
        else             v = cv[e] * bv[e];
        // u < 0.9f  <=>  bits>>9 < 7549747  <=>  bits < 7549747*512
        ov[e] = (bits < 3865470464u) ? v * INVKEEP : 0.0f;
      }
      *(float4*)&out[nb] = make_float4(ov[0], ov[1], ov[2], ov[3]);
    }
  }
}

extern "C" void kernel_launch(void* const* d_in, const int* in_sizes, int n_in,
                              void* d_out, int out_size, void* d_ws, size_t ws_size,
                              hipStream_t stream) {
  (void)in_sizes; (void)n_in; (void)out_size; (void)ws_size;
  const float* C = (const float*)d_in[0];
  const float* Q = (const float*)d_in[1];
  const float* W = (const float*)d_in[2];
  float* out = (float*)d_out;
  float* ws  = (float*)d_ws;

  hipLaunchKernelGGL(k_prep,  dim3(256),  dim3(256), 0, stream, Q, W, ws);
  hipLaunchKernelGGL(k_s,     dim3(512),  dim3(256), 0, stream, C, ws);
  hipLaunchKernelGGL(k_cred,  dim3(NB),   dim3(128), 0, stream, ws);
  hipLaunchKernelGGL(k_m,     dim3(512),  dim3(256), 0, stream, C, ws);
  hipLaunchKernelGGL(k_final, dim3(8192), dim3(256), 0, stream, C, ws, out);
}